// Round 12
// baseline (351.806 us; speedup 1.0000x reference)
//
#include <hip/hip_runtime.h>

// ---------------------------------------------------------------------------
// BipartiteLayer: xp = x@W_in+b ; s = exp(-|[xp_i[s],xp_m[e]]@W_score+b|) ;
// scatter mean/max of xp_pair*s ; h = relu([x,xp,mean,max]@W_out+b)
//
// R11: R10 split pipeline, with the 112-us 2-block serial k_scan replaced by
// a deterministic 3-phase parallel scan (blk-reduce -> top-scan -> blk-write).
// Same ordered CSR bytes -> downstream kernels byte-identical.
//
// Pipeline (slab-chunked H to fit adaptive workspace):
//   k_prep_wt     : W (f32, KxN) -> Wt (N rows x K, bf16) transpose
//   k_gemm_in     : MFMA bf16 K=128 one-shot; fused bias, xp store, a=xp.Ws
//   k_deg / k_scan_blk / k_scan_top / k_scan_wr / k_fill : sorted CSR build
//   per slab:
//     k_agg       : wave-per-node CSR gather-reduce -> H slab rows (1408 bf16)
//     k_gemm_out  : bf16 MFMA, 64x128 tile, BK=64 dbuf LDS via global_load_lds
// ---------------------------------------------------------------------------

typedef __attribute__((ext_vector_type(8))) short bf16x8;   // 8 bf16 = 4 VGPR
typedef __attribute__((ext_vector_type(4))) float f32x4;

static __device__ __forceinline__ unsigned short f2bf(float f) {
  unsigned int u = __float_as_uint(f);
  u = (u + 0x7FFFu + ((u >> 16) & 1u)) >> 16;   // RNE
  return (unsigned short)u;
}
static __device__ __forceinline__ float bf2f(unsigned short s) {
  return __uint_as_float(((unsigned int)s) << 16);
}

#define GLD16(gp, lp)                                                        \
  __builtin_amdgcn_global_load_lds(                                          \
      (const __attribute__((address_space(1))) void*)(gp),                   \
      (__attribute__((address_space(3))) void*)(lp), 16, 0, 0)

// ---- transpose W (KxNcol f32) -> Wt[col][k] bf16 ---------------------------
__global__ void k_prep_wt(const float* __restrict__ Wo,
                          unsigned short* __restrict__ Wt, int K, int Ncol) {
  int idx = blockIdx.x * blockDim.x + threadIdx.x;
  if (idx >= K * Ncol) return;
  int k = idx / Ncol, c = idx % Ncol;
  Wt[(size_t)c * K + k] = f2bf(Wo[idx]);
}

// ---- input GEMM (MFMA): [N,128]f32 @ [128,256] -> xp bf16, a=xp.Ws --------
__global__ __launch_bounds__(256) void k_gemm_in(
    const float* __restrict__ x, const unsigned short* __restrict__ Wint,
    const float* __restrict__ bias, const float* __restrict__ Wsc,
    unsigned short* __restrict__ xp, float* __restrict__ a_out, int N) {
  __shared__ __align__(16) unsigned short Ab[64 * 16 * 8];    // 16 KB
  __shared__ __align__(16) unsigned short Bb[256 * 16 * 8];   // 64 KB
  const int tid = threadIdx.x;
  const int l = tid & 63;
  const int lr = l & 15, lg = l >> 4;
  const int w = tid >> 6, wr = w >> 1, wc = w & 1;
  const int r0 = blockIdx.x * 64;
  const int wbase = tid & 192;                  // w*64, wave-uniform

#pragma unroll
  for (int i = 0; i < 16; ++i) {                // B: 256 rows x 16 chunks
    int g = i * 256 + tid;
    int row = g >> 4, c = g & 15;
    int sc = c ^ (row & 7);
    GLD16(Wint + (size_t)row * 128 + sc * 8,
          &Bb[(size_t)(i * 256 + wbase) * 8]);
  }
#pragma unroll
  for (int i = 0; i < 4; ++i) {                 // A: reg-stage f32->bf16
    int g = i * 256 + tid;
    int row = g >> 4, c = g & 15;
    int ar = min(r0 + row, N - 1);
    const float* src = x + (size_t)ar * 128 + c * 8;
    float4 u = *(const float4*)src;
    float4 v = *(const float4*)(src + 4);
    bf16x8 h;
    h[0] = (short)f2bf(u.x); h[1] = (short)f2bf(u.y);
    h[2] = (short)f2bf(u.z); h[3] = (short)f2bf(u.w);
    h[4] = (short)f2bf(v.x); h[5] = (short)f2bf(v.y);
    h[6] = (short)f2bf(v.z); h[7] = (short)f2bf(v.w);
    *(bf16x8*)&Ab[(size_t)(row * 16 + (c ^ (row & 7))) * 8] = h;
  }
  __syncthreads();

  f32x4 acc[2][8];
#pragma unroll
  for (int m = 0; m < 2; ++m)
#pragma unroll
    for (int t = 0; t < 8; ++t) {
      f32x4 z = {0.f, 0.f, 0.f, 0.f};
      acc[m][t] = z;
    }
#pragma unroll
  for (int kk = 0; kk < 4; ++kk) {
    int chq = kk * 4 + lg;
    bf16x8 a[2], bt[8];
#pragma unroll
    for (int m = 0; m < 2; ++m) {
      int row = wr * 32 + m * 16 + lr;
      a[m] = *(const bf16x8*)&Ab[(row * 16 + (chq ^ (row & 7))) * 8];
    }
#pragma unroll
    for (int t = 0; t < 8; ++t) {
      int row = wc * 128 + t * 16 + lr;
      bt[t] = *(const bf16x8*)&Bb[(row * 16 + (chq ^ (row & 7))) * 8];
    }
#pragma unroll
    for (int m = 0; m < 2; ++m)
#pragma unroll
      for (int t = 0; t < 8; ++t)
        acc[m][t] = __builtin_amdgcn_mfma_f32_16x16x32_bf16(
            a[m], bt[t], acc[m][t], 0, 0, 0);
  }

  float wscv[8], bb[8];
#pragma unroll
  for (int t = 0; t < 8; ++t) {
    int c = wc * 128 + t * 16 + lr;
    wscv[t] = Wsc[c];
    bb[t] = bias[c];
  }
#pragma unroll
  for (int m = 0; m < 2; ++m) {
    int rb = r0 + wr * 32 + m * 16 + lg * 4;    // C/D: col=lane&15, row=lg*4+reg
    float p0 = 0.f, p1 = 0.f, p2 = 0.f, p3 = 0.f;
#pragma unroll
    for (int t = 0; t < 8; ++t) {
      int c = wc * 128 + t * 16 + lr;
      float v0 = acc[m][t][0] + bb[t];
      float v1 = acc[m][t][1] + bb[t];
      float v2 = acc[m][t][2] + bb[t];
      float v3 = acc[m][t][3] + bb[t];
      if (rb + 0 < N) xp[(size_t)(rb + 0) * 256 + c] = f2bf(v0);
      if (rb + 1 < N) xp[(size_t)(rb + 1) * 256 + c] = f2bf(v1);
      if (rb + 2 < N) xp[(size_t)(rb + 2) * 256 + c] = f2bf(v2);
      if (rb + 3 < N) xp[(size_t)(rb + 3) * 256 + c] = f2bf(v3);
      p0 = fmaf(v0, wscv[t], p0); p1 = fmaf(v1, wscv[t], p1);
      p2 = fmaf(v2, wscv[t], p2); p3 = fmaf(v3, wscv[t], p3);
    }
#pragma unroll
    for (int off = 1; off < 16; off <<= 1) {
      p0 += __shfl_xor(p0, off); p1 += __shfl_xor(p1, off);
      p2 += __shfl_xor(p2, off); p3 += __shfl_xor(p3, off);
    }
    if (lr == 0) {
      if (rb + 0 < N) atomicAdd(a_out + rb + 0, p0);
      if (rb + 1 < N) atomicAdd(a_out + rb + 1, p1);
      if (rb + 2 < N) atomicAdd(a_out + rb + 2, p2);
      if (rb + 3 < N) atomicAdd(a_out + rb + 3, p3);
    }
  }
}

// ---- CSR build: degree histogram ------------------------------------------
__global__ void k_deg(const int* __restrict__ es, const int* __restrict__ ee,
                      int E, int* __restrict__ deg_i, int* __restrict__ deg_m) {
  int e = blockIdx.x * blockDim.x + threadIdx.x;
  if (e >= E) return;
  atomicAdd(deg_i + es[e], 1);
  atomicAdd(deg_m + ee[e], 1);
}

// ---- CSR scan phase 1: per-block (256 nodes) degree sum --------------------
__global__ __launch_bounds__(256) void k_scan_blk(
    const int* __restrict__ deg, int* __restrict__ blksum, int n) {
  __shared__ int sm[256];
  int t = threadIdx.x;
  int i = blockIdx.x * 256 + t;
  sm[t] = (i < n) ? deg[i] : 0;
  __syncthreads();
#pragma unroll
  for (int off = 128; off; off >>= 1) {
    if (t < off) sm[t] += sm[t + off];
    __syncthreads();
  }
  if (t == 0) blksum[blockIdx.x] = sm[0];
}

// ---- CSR scan phase 2: exclusive scan of block sums (<=1024 blocks/side) --
__global__ __launch_bounds__(1024) void k_scan_top(
    const int* __restrict__ bs_i, int* __restrict__ bb_i, int nbi,
    const int* __restrict__ bs_m, int* __restrict__ bb_m, int nbm) {
  const int* bs = blockIdx.x ? bs_m : bs_i;
  int* bb = blockIdx.x ? bb_m : bb_i;
  int nb = blockIdx.x ? nbm : nbi;
  __shared__ int sm[1024];
  int t = threadIdx.x;
  int d = (t < nb) ? bs[t] : 0;
  sm[t] = d;
  __syncthreads();
  for (int off = 1; off < 1024; off <<= 1) {    // Hillis-Steele inclusive
    int v = (t >= off) ? sm[t - off] : 0;
    __syncthreads();
    sm[t] += v;
    __syncthreads();
  }
  if (t < nb) bb[t] = sm[t] - d;                // exclusive
}

// ---- CSR scan phase 3: per-block exclusive scan + base -> rp, cur ---------
__global__ __launch_bounds__(256) void k_scan_wr(
    const int* __restrict__ deg, const int* __restrict__ blkbase,
    int* __restrict__ rp, int* __restrict__ cur, int n, int E) {
  __shared__ int sm[256];
  int t = threadIdx.x;
  int i = blockIdx.x * 256 + t;
  int d = (i < n) ? deg[i] : 0;
  sm[t] = d;
  __syncthreads();
  for (int off = 1; off < 256; off <<= 1) {     // Hillis-Steele inclusive
    int v = (t >= off) ? sm[t - off] : 0;
    __syncthreads();
    sm[t] += v;
    __syncthreads();
  }
  if (i < n) {
    int v = blkbase[blockIdx.x] + sm[t] - d;    // exclusive + block base
    rp[i] = v; cur[i] = v;
  }
  if (i == 0) rp[n] = E;
}

// ---- CSR build: score + fill ----------------------------------------------
__global__ void k_fill(const int* __restrict__ es, const int* __restrict__ ee,
                       int E, const float* __restrict__ a_i,
                       const float* __restrict__ a_m,
                       const float* __restrict__ bsc,
                       int* __restrict__ cur_i, int* __restrict__ col_i,
                       float* __restrict__ sv_i,
                       int* __restrict__ cur_m, int* __restrict__ col_m,
                       float* __restrict__ sv_m) {
  int e = blockIdx.x * blockDim.x + threadIdx.x;
  if (e >= E) return;
  int s = es[e], m = ee[e];
  float sc = expf(-fabsf(a_i[s] + a_m[m] + bsc[0]));
  int pi = atomicAdd(cur_i + s, 1);
  col_i[pi] = m; sv_i[pi] = sc;
  int pm = atomicAdd(cur_m + m, 1);
  col_m[pm] = s; sv_m[pm] = sc;
}

// ---- wave-per-node CSR aggregation -> H slab row (1408 bf16) ---------------
// H = [x(128) | xp(256) | mean(512) | max(512)]; 4 gathers in flight.
__global__ __launch_bounds__(256) void k_agg(
    const float* __restrict__ x_own, const unsigned short* __restrict__ xp_own,
    const unsigned short* __restrict__ xp_oth,
    const int* __restrict__ rowptr, const int* __restrict__ col,
    const float* __restrict__ sv, unsigned short* __restrict__ H,
    int base, int cnt, int own_off, int oth_off) {
  int local = blockIdx.x * 4 + (threadIdx.x >> 6);
  if (local >= cnt) return;                      // wave-uniform
  int node = base + local;
  int l = threadIdx.x & 63;
  ushort4 xo = *(const ushort4*)(xp_own + (size_t)node * 256 + 4 * l);
  float xp0 = bf2f(xo.x), xp1 = bf2f(xo.y), xp2 = bf2f(xo.z), xp3 = bf2f(xo.w);
  float2 xv = *(const float2*)(x_own + (size_t)node * 128 + 2 * l);
  unsigned short* Hr = H + (size_t)local * 1408;
  *(ushort2*)(Hr + 2 * l) = make_ushort2(f2bf(xv.x), f2bf(xv.y));
  *(ushort4*)(Hr + 128 + 4 * l) = xo;

  float sum_s = 0.f, mx_s = -1e30f, mn_s = 1e30f;
  float sv0 = 0.f, sv1 = 0.f, sv2 = 0.f, sv3 = 0.f;
  float mv0 = -1e30f, mv1 = -1e30f, mv2 = -1e30f, mv3 = -1e30f;
  int jb = rowptr[node], je = rowptr[node + 1];
  int dg = je - jb;
  int j = jb;
  for (; j + 3 < je; j += 4) {                   // 4 independent gathers
    int o0 = col[j], o1 = col[j + 1], o2 = col[j + 2], o3 = col[j + 3];
    float s0 = sv[j], s1 = sv[j + 1], s2 = sv[j + 2], s3 = sv[j + 3];
    ushort4 g0 = *(const ushort4*)(xp_oth + (size_t)o0 * 256 + 4 * l);
    ushort4 g1 = *(const ushort4*)(xp_oth + (size_t)o1 * 256 + 4 * l);
    ushort4 g2 = *(const ushort4*)(xp_oth + (size_t)o2 * 256 + 4 * l);
    ushort4 g3 = *(const ushort4*)(xp_oth + (size_t)o3 * 256 + 4 * l);
    float f0, f1, f2, f3;
    f0 = bf2f(g0.x); f1 = bf2f(g0.y); f2 = bf2f(g0.z); f3 = bf2f(g0.w);
    sv0 = fmaf(s0, f0, sv0); sv1 = fmaf(s0, f1, sv1);
    sv2 = fmaf(s0, f2, sv2); sv3 = fmaf(s0, f3, sv3);
    mv0 = fmaxf(mv0, s0 * f0); mv1 = fmaxf(mv1, s0 * f1);
    mv2 = fmaxf(mv2, s0 * f2); mv3 = fmaxf(mv3, s0 * f3);
    f0 = bf2f(g1.x); f1 = bf2f(g1.y); f2 = bf2f(g1.z); f3 = bf2f(g1.w);
    sv0 = fmaf(s1, f0, sv0); sv1 = fmaf(s1, f1, sv1);
    sv2 = fmaf(s1, f2, sv2); sv3 = fmaf(s1, f3, sv3);
    mv0 = fmaxf(mv0, s1 * f0); mv1 = fmaxf(mv1, s1 * f1);
    mv2 = fmaxf(mv2, s1 * f2); mv3 = fmaxf(mv3, s1 * f3);
    f0 = bf2f(g2.x); f1 = bf2f(g2.y); f2 = bf2f(g2.z); f3 = bf2f(g2.w);
    sv0 = fmaf(s2, f0, sv0); sv1 = fmaf(s2, f1, sv1);
    sv2 = fmaf(s2, f2, sv2); sv3 = fmaf(s2, f3, sv3);
    mv0 = fmaxf(mv0, s2 * f0); mv1 = fmaxf(mv1, s2 * f1);
    mv2 = fmaxf(mv2, s2 * f2); mv3 = fmaxf(mv3, s2 * f3);
    f0 = bf2f(g3.x); f1 = bf2f(g3.y); f2 = bf2f(g3.z); f3 = bf2f(g3.w);
    sv0 = fmaf(s3, f0, sv0); sv1 = fmaf(s3, f1, sv1);
    sv2 = fmaf(s3, f2, sv2); sv3 = fmaf(s3, f3, sv3);
    mv0 = fmaxf(mv0, s3 * f0); mv1 = fmaxf(mv1, s3 * f1);
    mv2 = fmaxf(mv2, s3 * f2); mv3 = fmaxf(mv3, s3 * f3);
    sum_s += (s0 + s1) + (s2 + s3);
    mx_s = fmaxf(mx_s, fmaxf(fmaxf(s0, s1), fmaxf(s2, s3)));
    mn_s = fminf(mn_s, fminf(fminf(s0, s1), fminf(s2, s3)));
  }
  for (; j < je; ++j) {                          // tail 0..3
    int o0 = col[j];
    float s0 = sv[j];
    ushort4 g0 = *(const ushort4*)(xp_oth + (size_t)o0 * 256 + 4 * l);
    float f0 = bf2f(g0.x), f1 = bf2f(g0.y), f2 = bf2f(g0.z), f3 = bf2f(g0.w);
    sv0 = fmaf(s0, f0, sv0); sv1 = fmaf(s0, f1, sv1);
    sv2 = fmaf(s0, f2, sv2); sv3 = fmaf(s0, f3, sv3);
    mv0 = fmaxf(mv0, s0 * f0); mv1 = fmaxf(mv1, s0 * f1);
    mv2 = fmaxf(mv2, s0 * f2); mv3 = fmaxf(mv3, s0 * f3);
    sum_s += s0; mx_s = fmaxf(mx_s, s0); mn_s = fminf(mn_s, s0);
  }
  float inv = 1.f / (float)(dg > 0 ? dg : 1);
  float ss = sum_s * inv;
  *(ushort4*)(Hr + 384 + own_off + 4 * l) = make_ushort4(
      f2bf(xp0 * ss), f2bf(xp1 * ss), f2bf(xp2 * ss), f2bf(xp3 * ss));
  *(ushort4*)(Hr + 384 + oth_off + 4 * l) = make_ushort4(
      f2bf(sv0 * inv), f2bf(sv1 * inv), f2bf(sv2 * inv), f2bf(sv3 * inv));
  float a0, a1, a2, a3;
  if (dg > 0) {
    a0 = fmaxf(fmaxf(xp0 * mx_s, xp0 * mn_s), 0.f);
    a1 = fmaxf(fmaxf(xp1 * mx_s, xp1 * mn_s), 0.f);
    a2 = fmaxf(fmaxf(xp2 * mx_s, xp2 * mn_s), 0.f);
    a3 = fmaxf(fmaxf(xp3 * mx_s, xp3 * mn_s), 0.f);
  } else {
    a0 = a1 = a2 = a3 = 0.f;
  }
  *(ushort4*)(Hr + 896 + own_off + 4 * l) =
      make_ushort4(f2bf(a0), f2bf(a1), f2bf(a2), f2bf(a3));
  *(ushort4*)(Hr + 896 + oth_off + 4 * l) =
      make_ushort4(f2bf(fmaxf(mv0, 0.f)), f2bf(fmaxf(mv1, 0.f)),
                   f2bf(fmaxf(mv2, 0.f)), f2bf(fmaxf(mv3, 0.f)));
}

// ---- output GEMM: [cnt,1408]bf16 @ Wt[128][1408]bf16 + b, relu -> f32 -----
__global__ __launch_bounds__(256) void k_gemm_out(
    const unsigned short* __restrict__ H, const unsigned short* __restrict__ Wt,
    const float* __restrict__ bias, float* __restrict__ out, int Nloc) {
  __shared__ unsigned short Ab[2][64 * 64];     //  8 KB x2
  __shared__ unsigned short Bb[2][128 * 64];    // 16 KB x2
  const int tid = threadIdx.x;
  const int l = tid & 63;
  const int lr = l & 15, lg = l >> 4;
  const int w = tid >> 6, wr = w >> 1, wc = w & 1;
  const int r0 = blockIdx.x * 64;
  const int wbase = tid & 192;                  // w*64, wave-uniform

  f32x4 acc[2][4];
#pragma unroll
  for (int m = 0; m < 2; ++m)
#pragma unroll
    for (int t = 0; t < 4; ++t) {
      f32x4 z = {0.f, 0.f, 0.f, 0.f};
      acc[m][t] = z;
    }

  auto stage = [&](int b, int kb) {
#pragma unroll
    for (int i = 0; i < 2; ++i) {               // A: 64 rows x 8 chunks
      int g = i * 256 + tid;
      int row = g >> 3, c = g & 7;
      int sc = c ^ (row & 7);
      GLD16(H + (size_t)(r0 + row) * 1408 + kb + sc * 8,
            &Ab[b][(size_t)(i * 256 + wbase) * 8]);
    }
#pragma unroll
    for (int i = 0; i < 4; ++i) {               // B: 128 rows x 8 chunks
      int g = i * 256 + tid;
      int row = g >> 3, c = g & 7;
      int sc = c ^ (row & 7);
      GLD16(Wt + (size_t)row * 1408 + kb + sc * 8,
            &Bb[b][(size_t)(i * 256 + wbase) * 8]);
    }
  };

  auto compute = [&](int b) {
#pragma unroll
    for (int kk = 0; kk < 2; ++kk) {
      int chq = kk * 4 + lg;
      bf16x8 a[2], bt[4];
#pragma unroll
      for (int m = 0; m < 2; ++m) {
        int row = wr * 32 + m * 16 + lr;
        a[m] = *(const bf16x8*)&Ab[b][(row * 8 + (chq ^ (row & 7))) * 8];
      }
#pragma unroll
      for (int t = 0; t < 4; ++t) {
        int row = wc * 64 + t * 16 + lr;
        bt[t] = *(const bf16x8*)&Bb[b][(row * 8 + (chq ^ (row & 7))) * 8];
      }
#pragma unroll
      for (int m = 0; m < 2; ++m)
#pragma unroll
        for (int t = 0; t < 4; ++t)
          acc[m][t] = __builtin_amdgcn_mfma_f32_16x16x32_bf16(
              a[m], bt[t], acc[m][t], 0, 0, 0);
    }
  };

  stage(0, 0);
  __syncthreads();
  int cur = 0;
  for (int t = 0; t < 22; ++t) {                // 22 * 64 = K = 1408
    if (t < 21) stage(cur ^ 1, (t + 1) * 64);
    compute(cur);
    __syncthreads();
    cur ^= 1;
  }

#pragma unroll
  for (int m = 0; m < 2; ++m) {
    int rb = r0 + wr * 32 + m * 16 + lg * 4;    // C/D: col=lane&15, row=lg*4+reg
#pragma unroll
    for (int t = 0; t < 4; ++t) {
      int c = wc * 64 + t * 16 + lr;
      float bbias = bias[c];
#pragma unroll
      for (int r = 0; r < 4; ++r) {
        int rr = rb + r;
        if (rr < Nloc) out[(size_t)rr * 128 + c] = fmaxf(acc[m][t][r] + bbias, 0.f);
      }
    }
  }
}

extern "C" void kernel_launch(void* const* d_in, const int* in_sizes, int n_in,
                              void* d_out, int out_size, void* d_ws,
                              size_t ws_size, hipStream_t stream) {
  const float* x_i  = (const float*)d_in[0];
  const float* x_m  = (const float*)d_in[1];
  const int*   ei   = (const int*)d_in[2];
  const float* Wi_i = (const float*)d_in[3];
  const float* bi_i = (const float*)d_in[4];
  const float* Wi_m = (const float*)d_in[5];
  const float* bi_m = (const float*)d_in[6];
  const float* Wsc  = (const float*)d_in[7];
  const float* bsc  = (const float*)d_in[8];
  const float* Wo_i = (const float*)d_in[9];
  const float* bo_i = (const float*)d_in[10];
  const float* Wo_m = (const float*)d_in[11];
  const float* bo_m = (const float*)d_in[12];
  float* out = (float*)d_out;

  int Ni = in_sizes[0] / 128, Nm = in_sizes[1] / 128, E = in_sizes[2] / 2;
  const int* es = ei;
  const int* ee = ei + E;
  int nbi = (Ni + 255) / 256, nbm = (Nm + 255) / 256;   // <= 1024 assumed

  char* p = (char*)d_ws;
  auto alloc = [&](size_t bytes) {
    char* q = p;
    p += (bytes + 255) & ~(size_t)255;
    return q;
  };
  unsigned short* xp_i = (unsigned short*)alloc((size_t)Ni * 256 * 2);
  unsigned short* xp_m = (unsigned short*)alloc((size_t)Nm * 256 * 2);
  float* a_i   = (float*)alloc((size_t)Ni * 4);
  float* a_m   = (float*)alloc((size_t)Nm * 4);
  int* deg_i   = (int*)alloc((size_t)Ni * 4);
  int* deg_m   = (int*)alloc((size_t)Nm * 4);
  int* rp_i    = (int*)alloc((size_t)(Ni + 1) * 4);
  int* rp_m    = (int*)alloc((size_t)(Nm + 1) * 4);
  int* cur_i   = (int*)alloc((size_t)Ni * 4);
  int* cur_m   = (int*)alloc((size_t)Nm * 4);
  int* bs_i    = (int*)alloc((size_t)nbi * 4);
  int* bs_m    = (int*)alloc((size_t)nbm * 4);
  int* bb_i    = (int*)alloc((size_t)nbi * 4);
  int* bb_m    = (int*)alloc((size_t)nbm * 4);
  int* col_i   = (int*)alloc((size_t)E * 4);
  int* col_m   = (int*)alloc((size_t)E * 4);
  float* sv_i  = (float*)alloc((size_t)E * 4);
  float* sv_m  = (float*)alloc((size_t)E * 4);
  unsigned short* Wt_i = (unsigned short*)alloc((size_t)128 * 1408 * 2);
  unsigned short* Wt_m = (unsigned short*)alloc((size_t)128 * 1408 * 2);
  unsigned short* Wint_i = (unsigned short*)alloc((size_t)256 * 128 * 2);
  unsigned short* Wint_m = (unsigned short*)alloc((size_t)256 * 128 * 2);

  size_t used = (size_t)(p - (char*)d_ws);
  if (used + 256 > ws_size) return;
  size_t avail = ws_size - used - 256;
  long long srows_ll = (long long)(avail / (1408 * 2));
  int maxN = (Ni > Nm ? Ni : Nm);
  int maxPad = (maxN + 127) & ~127;
  int S = (int)(srows_ll > maxPad ? maxPad : srows_ll);
  S &= ~127;
  if (S < 128) return;
  unsigned short* Hs = (unsigned short*)alloc((size_t)S * 1408 * 2);

  hipMemsetAsync(deg_i, 0, (size_t)Ni * 4, stream);
  hipMemsetAsync(deg_m, 0, (size_t)Nm * 4, stream);
  hipMemsetAsync(a_i, 0, (size_t)Ni * 4, stream);
  hipMemsetAsync(a_m, 0, (size_t)Nm * 4, stream);

  k_prep_wt<<<(1408 * 128 + 255) / 256, 256, 0, stream>>>(Wo_i, Wt_i, 1408, 128);
  k_prep_wt<<<(1408 * 128 + 255) / 256, 256, 0, stream>>>(Wo_m, Wt_m, 1408, 128);
  k_prep_wt<<<(128 * 256 + 255) / 256, 256, 0, stream>>>(Wi_i, Wint_i, 128, 256);
  k_prep_wt<<<(128 * 256 + 255) / 256, 256, 0, stream>>>(Wi_m, Wint_m, 128, 256);

  k_gemm_in<<<(Ni + 63) / 64, 256, 0, stream>>>(x_i, Wint_i, bi_i, Wsc, xp_i, a_i, Ni);
  k_gemm_in<<<(Nm + 63) / 64, 256, 0, stream>>>(x_m, Wint_m, bi_m, Wsc + 256, xp_m, a_m, Nm);

  k_deg<<<(E + 255) / 256, 256, 0, stream>>>(es, ee, E, deg_i, deg_m);
  k_scan_blk<<<nbi, 256, 0, stream>>>(deg_i, bs_i, Ni);
  k_scan_blk<<<nbm, 256, 0, stream>>>(deg_m, bs_m, Nm);
  k_scan_top<<<2, 1024, 0, stream>>>(bs_i, bb_i, nbi, bs_m, bb_m, nbm);
  k_scan_wr<<<nbi, 256, 0, stream>>>(deg_i, bb_i, rp_i, cur_i, Ni, E);
  k_scan_wr<<<nbm, 256, 0, stream>>>(deg_m, bb_m, rp_m, cur_m, Nm, E);
  k_fill<<<(E + 255) / 256, 256, 0, stream>>>(es, ee, E, a_i, a_m, bsc,
                                              cur_i, col_i, sv_i,
                                              cur_m, col_m, sv_m);

  // intt side: own half of pooled cols at [0,256), gathered (mvtx) at [256,512)
  for (int base = 0; base < Ni; base += S) {
    int cnt = Ni - base; if (cnt > S) cnt = S;
    k_agg<<<(cnt + 3) / 4, 256, 0, stream>>>(x_i, xp_i, xp_m, rp_i, col_i,
                                             sv_i, Hs, base, cnt, 0, 256);
    k_gemm_out<<<(cnt + 63) / 64, 256, 0, stream>>>(Hs, Wt_i, bo_i,
                                                    out + (size_t)base * 128, cnt);
  }
  // mvtx side: gathered (intt) at [0,256), own half at [256,512)
  float* out_m = out + (size_t)Ni * 128;
  for (int base = 0; base < Nm; base += S) {
    int cnt = Nm - base; if (cnt > S) cnt = S;
    k_agg<<<(cnt + 3) / 4, 256, 0, stream>>>(x_m, xp_m, xp_i, rp_m, col_m,
                                             sv_m, Hs, base, cnt, 256, 0);
    k_gemm_out<<<(cnt + 63) / 64, 256, 0, stream>>>(Hs, Wt_m, bo_m,
                                                    out_m + (size_t)base * 128, cnt);
  }
}

// Round 13
// 334.189 us; speedup vs baseline: 1.0527x; 1.0527x over previous
//
#include <hip/hip_runtime.h>

// ---------------------------------------------------------------------------
// BipartiteLayer: xp = x@W_in+b ; s = exp(-|[xp_i[s],xp_m[e]]@W_score+b|) ;
// scatter mean/max of xp_pair*s ; h = relu([x,xp,mean,max]@W_out+b)
//
// R13: k_gemm_out 4-wave -> 8-wave (512 thr) on the same 64x128 tile.
// R12 showed 392 blocks x 4 waves = 1.5 waves/SIMD: the 22 per-K-step
// vmcnt(0)+barrier drains had nothing to overlap with (occ 20%, hbm 20%).
// 8 waves doubles co-resident waves; bytes/MFMA order unchanged.
//
// Pipeline (slab-chunked H to fit adaptive workspace):
//   k_prep_wt     : W (f32, KxN) -> Wt (N rows x K, bf16) transpose
//   k_gemm_in     : MFMA bf16 K=128 one-shot; fused bias, xp store, a=xp.Ws
//   k_deg / k_scan_blk / k_scan_top / k_scan_wr / k_fill : sorted CSR build
//   per slab:
//     k_agg       : wave-per-node CSR gather-reduce -> H slab rows (1408 bf16)
//     k_gemm_out  : bf16 MFMA, 64x128 tile, 8 waves, BK=64 dbuf global_load_lds
// ---------------------------------------------------------------------------

typedef __attribute__((ext_vector_type(8))) short bf16x8;   // 8 bf16 = 4 VGPR
typedef __attribute__((ext_vector_type(4))) float f32x4;

static __device__ __forceinline__ unsigned short f2bf(float f) {
  unsigned int u = __float_as_uint(f);
  u = (u + 0x7FFFu + ((u >> 16) & 1u)) >> 16;   // RNE
  return (unsigned short)u;
}
static __device__ __forceinline__ float bf2f(unsigned short s) {
  return __uint_as_float(((unsigned int)s) << 16);
}

#define GLD16(gp, lp)                                                        \
  __builtin_amdgcn_global_load_lds(                                          \
      (const __attribute__((address_space(1))) void*)(gp),                   \
      (__attribute__((address_space(3))) void*)(lp), 16, 0, 0)

// ---- transpose W (KxNcol f32) -> Wt[col][k] bf16 ---------------------------
__global__ void k_prep_wt(const float* __restrict__ Wo,
                          unsigned short* __restrict__ Wt, int K, int Ncol) {
  int idx = blockIdx.x * blockDim.x + threadIdx.x;
  if (idx >= K * Ncol) return;
  int k = idx / Ncol, c = idx % Ncol;
  Wt[(size_t)c * K + k] = f2bf(Wo[idx]);
}

// ---- input GEMM (MFMA): [N,128]f32 @ [128,256] -> xp bf16, a=xp.Ws --------
__global__ __launch_bounds__(256) void k_gemm_in(
    const float* __restrict__ x, const unsigned short* __restrict__ Wint,
    const float* __restrict__ bias, const float* __restrict__ Wsc,
    unsigned short* __restrict__ xp, float* __restrict__ a_out, int N) {
  __shared__ __align__(16) unsigned short Ab[64 * 16 * 8];    // 16 KB
  __shared__ __align__(16) unsigned short Bb[256 * 16 * 8];   // 64 KB
  const int tid = threadIdx.x;
  const int l = tid & 63;
  const int lr = l & 15, lg = l >> 4;
  const int w = tid >> 6, wr = w >> 1, wc = w & 1;
  const int r0 = blockIdx.x * 64;
  const int wbase = tid & 192;                  // w*64, wave-uniform

#pragma unroll
  for (int i = 0; i < 16; ++i) {                // B: 256 rows x 16 chunks
    int g = i * 256 + tid;
    int row = g >> 4, c = g & 15;
    int sc = c ^ (row & 7);
    GLD16(Wint + (size_t)row * 128 + sc * 8,
          &Bb[(size_t)(i * 256 + wbase) * 8]);
  }
#pragma unroll
  for (int i = 0; i < 4; ++i) {                 // A: reg-stage f32->bf16
    int g = i * 256 + tid;
    int row = g >> 4, c = g & 15;
    int ar = min(r0 + row, N - 1);
    const float* src = x + (size_t)ar * 128 + c * 8;
    float4 u = *(const float4*)src;
    float4 v = *(const float4*)(src + 4);
    bf16x8 h;
    h[0] = (short)f2bf(u.x); h[1] = (short)f2bf(u.y);
    h[2] = (short)f2bf(u.z); h[3] = (short)f2bf(u.w);
    h[4] = (short)f2bf(v.x); h[5] = (short)f2bf(v.y);
    h[6] = (short)f2bf(v.z); h[7] = (short)f2bf(v.w);
    *(bf16x8*)&Ab[(size_t)(row * 16 + (c ^ (row & 7))) * 8] = h;
  }
  __syncthreads();

  f32x4 acc[2][8];
#pragma unroll
  for (int m = 0; m < 2; ++m)
#pragma unroll
    for (int t = 0; t < 8; ++t) {
      f32x4 z = {0.f, 0.f, 0.f, 0.f};
      acc[m][t] = z;
    }
#pragma unroll
  for (int kk = 0; kk < 4; ++kk) {
    int chq = kk * 4 + lg;
    bf16x8 a[2], bt[8];
#pragma unroll
    for (int m = 0; m < 2; ++m) {
      int row = wr * 32 + m * 16 + lr;
      a[m] = *(const bf16x8*)&Ab[(row * 16 + (chq ^ (row & 7))) * 8];
    }
#pragma unroll
    for (int t = 0; t < 8; ++t) {
      int row = wc * 128 + t * 16 + lr;
      bt[t] = *(const bf16x8*)&Bb[(row * 16 + (chq ^ (row & 7))) * 8];
    }
#pragma unroll
    for (int m = 0; m < 2; ++m)
#pragma unroll
      for (int t = 0; t < 8; ++t)
        acc[m][t] = __builtin_amdgcn_mfma_f32_16x16x32_bf16(
            a[m], bt[t], acc[m][t], 0, 0, 0);
  }

  float wscv[8], bb[8];
#pragma unroll
  for (int t = 0; t < 8; ++t) {
    int c = wc * 128 + t * 16 + lr;
    wscv[t] = Wsc[c];
    bb[t] = bias[c];
  }
#pragma unroll
  for (int m = 0; m < 2; ++m) {
    int rb = r0 + wr * 32 + m * 16 + lg * 4;    // C/D: col=lane&15, row=lg*4+reg
    float p0 = 0.f, p1 = 0.f, p2 = 0.f, p3 = 0.f;
#pragma unroll
    for (int t = 0; t < 8; ++t) {
      int c = wc * 128 + t * 16 + lr;
      float v0 = acc[m][t][0] + bb[t];
      float v1 = acc[m][t][1] + bb[t];
      float v2 = acc[m][t][2] + bb[t];
      float v3 = acc[m][t][3] + bb[t];
      if (rb + 0 < N) xp[(size_t)(rb + 0) * 256 + c] = f2bf(v0);
      if (rb + 1 < N) xp[(size_t)(rb + 1) * 256 + c] = f2bf(v1);
      if (rb + 2 < N) xp[(size_t)(rb + 2) * 256 + c] = f2bf(v2);
      if (rb + 3 < N) xp[(size_t)(rb + 3) * 256 + c] = f2bf(v3);
      p0 = fmaf(v0, wscv[t], p0); p1 = fmaf(v1, wscv[t], p1);
      p2 = fmaf(v2, wscv[t], p2); p3 = fmaf(v3, wscv[t], p3);
    }
#pragma unroll
    for (int off = 1; off < 16; off <<= 1) {
      p0 += __shfl_xor(p0, off); p1 += __shfl_xor(p1, off);
      p2 += __shfl_xor(p2, off); p3 += __shfl_xor(p3, off);
    }
    if (lr == 0) {
      if (rb + 0 < N) atomicAdd(a_out + rb + 0, p0);
      if (rb + 1 < N) atomicAdd(a_out + rb + 1, p1);
      if (rb + 2 < N) atomicAdd(a_out + rb + 2, p2);
      if (rb + 3 < N) atomicAdd(a_out + rb + 3, p3);
    }
  }
}

// ---- CSR build: degree histogram ------------------------------------------
__global__ void k_deg(const int* __restrict__ es, const int* __restrict__ ee,
                      int E, int* __restrict__ deg_i, int* __restrict__ deg_m) {
  int e = blockIdx.x * blockDim.x + threadIdx.x;
  if (e >= E) return;
  atomicAdd(deg_i + es[e], 1);
  atomicAdd(deg_m + ee[e], 1);
}

// ---- CSR scan phase 1: per-block (256 nodes) degree sum --------------------
__global__ __launch_bounds__(256) void k_scan_blk(
    const int* __restrict__ deg, int* __restrict__ blksum, int n) {
  __shared__ int sm[256];
  int t = threadIdx.x;
  int i = blockIdx.x * 256 + t;
  sm[t] = (i < n) ? deg[i] : 0;
  __syncthreads();
#pragma unroll
  for (int off = 128; off; off >>= 1) {
    if (t < off) sm[t] += sm[t + off];
    __syncthreads();
  }
  if (t == 0) blksum[blockIdx.x] = sm[0];
}

// ---- CSR scan phase 2: exclusive scan of block sums (<=1024 blocks/side) --
__global__ __launch_bounds__(1024) void k_scan_top(
    const int* __restrict__ bs_i, int* __restrict__ bb_i, int nbi,
    const int* __restrict__ bs_m, int* __restrict__ bb_m, int nbm) {
  const int* bs = blockIdx.x ? bs_m : bs_i;
  int* bb = blockIdx.x ? bb_m : bb_i;
  int nb = blockIdx.x ? nbm : nbi;
  __shared__ int sm[1024];
  int t = threadIdx.x;
  int d = (t < nb) ? bs[t] : 0;
  sm[t] = d;
  __syncthreads();
  for (int off = 1; off < 1024; off <<= 1) {    // Hillis-Steele inclusive
    int v = (t >= off) ? sm[t - off] : 0;
    __syncthreads();
    sm[t] += v;
    __syncthreads();
  }
  if (t < nb) bb[t] = sm[t] - d;                // exclusive
}

// ---- CSR scan phase 3: per-block exclusive scan + base -> rp, cur ---------
__global__ __launch_bounds__(256) void k_scan_wr(
    const int* __restrict__ deg, const int* __restrict__ blkbase,
    int* __restrict__ rp, int* __restrict__ cur, int n, int E) {
  __shared__ int sm[256];
  int t = threadIdx.x;
  int i = blockIdx.x * 256 + t;
  int d = (i < n) ? deg[i] : 0;
  sm[t] = d;
  __syncthreads();
  for (int off = 1; off < 256; off <<= 1) {     // Hillis-Steele inclusive
    int v = (t >= off) ? sm[t - off] : 0;
    __syncthreads();
    sm[t] += v;
    __syncthreads();
  }
  if (i < n) {
    int v = blkbase[blockIdx.x] + sm[t] - d;    // exclusive + block base
    rp[i] = v; cur[i] = v;
  }
  if (i == 0) rp[n] = E;
}

// ---- CSR build: score + fill ----------------------------------------------
__global__ void k_fill(const int* __restrict__ es, const int* __restrict__ ee,
                       int E, const float* __restrict__ a_i,
                       const float* __restrict__ a_m,
                       const float* __restrict__ bsc,
                       int* __restrict__ cur_i, int* __restrict__ col_i,
                       float* __restrict__ sv_i,
                       int* __restrict__ cur_m, int* __restrict__ col_m,
                       float* __restrict__ sv_m) {
  int e = blockIdx.x * blockDim.x + threadIdx.x;
  if (e >= E) return;
  int s = es[e], m = ee[e];
  float sc = expf(-fabsf(a_i[s] + a_m[m] + bsc[0]));
  int pi = atomicAdd(cur_i + s, 1);
  col_i[pi] = m; sv_i[pi] = sc;
  int pm = atomicAdd(cur_m + m, 1);
  col_m[pm] = s; sv_m[pm] = sc;
}

// ---- wave-per-node CSR aggregation -> H slab row (1408 bf16) ---------------
// H = [x(128) | xp(256) | mean(512) | max(512)]; 4 gathers in flight.
__global__ __launch_bounds__(256) void k_agg(
    const float* __restrict__ x_own, const unsigned short* __restrict__ xp_own,
    const unsigned short* __restrict__ xp_oth,
    const int* __restrict__ rowptr, const int* __restrict__ col,
    const float* __restrict__ sv, unsigned short* __restrict__ H,
    int base, int cnt, int own_off, int oth_off) {
  int local = blockIdx.x * 4 + (threadIdx.x >> 6);
  if (local >= cnt) return;                      // wave-uniform
  int node = base + local;
  int l = threadIdx.x & 63;
  ushort4 xo = *(const ushort4*)(xp_own + (size_t)node * 256 + 4 * l);
  float xp0 = bf2f(xo.x), xp1 = bf2f(xo.y), xp2 = bf2f(xo.z), xp3 = bf2f(xo.w);
  float2 xv = *(const float2*)(x_own + (size_t)node * 128 + 2 * l);
  unsigned short* Hr = H + (size_t)local * 1408;
  *(ushort2*)(Hr + 2 * l) = make_ushort2(f2bf(xv.x), f2bf(xv.y));
  *(ushort4*)(Hr + 128 + 4 * l) = xo;

  float sum_s = 0.f, mx_s = -1e30f, mn_s = 1e30f;
  float sv0 = 0.f, sv1 = 0.f, sv2 = 0.f, sv3 = 0.f;
  float mv0 = -1e30f, mv1 = -1e30f, mv2 = -1e30f, mv3 = -1e30f;
  int jb = rowptr[node], je = rowptr[node + 1];
  int dg = je - jb;
  int j = jb;
  for (; j + 3 < je; j += 4) {                   // 4 independent gathers
    int o0 = col[j], o1 = col[j + 1], o2 = col[j + 2], o3 = col[j + 3];
    float s0 = sv[j], s1 = sv[j + 1], s2 = sv[j + 2], s3 = sv[j + 3];
    ushort4 g0 = *(const ushort4*)(xp_oth + (size_t)o0 * 256 + 4 * l);
    ushort4 g1 = *(const ushort4*)(xp_oth + (size_t)o1 * 256 + 4 * l);
    ushort4 g2 = *(const ushort4*)(xp_oth + (size_t)o2 * 256 + 4 * l);
    ushort4 g3 = *(const ushort4*)(xp_oth + (size_t)o3 * 256 + 4 * l);
    float f0, f1, f2, f3;
    f0 = bf2f(g0.x); f1 = bf2f(g0.y); f2 = bf2f(g0.z); f3 = bf2f(g0.w);
    sv0 = fmaf(s0, f0, sv0); sv1 = fmaf(s0, f1, sv1);
    sv2 = fmaf(s0, f2, sv2); sv3 = fmaf(s0, f3, sv3);
    mv0 = fmaxf(mv0, s0 * f0); mv1 = fmaxf(mv1, s0 * f1);
    mv2 = fmaxf(mv2, s0 * f2); mv3 = fmaxf(mv3, s0 * f3);
    f0 = bf2f(g1.x); f1 = bf2f(g1.y); f2 = bf2f(g1.z); f3 = bf2f(g1.w);
    sv0 = fmaf(s1, f0, sv0); sv1 = fmaf(s1, f1, sv1);
    sv2 = fmaf(s1, f2, sv2); sv3 = fmaf(s1, f3, sv3);
    mv0 = fmaxf(mv0, s1 * f0); mv1 = fmaxf(mv1, s1 * f1);
    mv2 = fmaxf(mv2, s1 * f2); mv3 = fmaxf(mv3, s1 * f3);
    f0 = bf2f(g2.x); f1 = bf2f(g2.y); f2 = bf2f(g2.z); f3 = bf2f(g2.w);
    sv0 = fmaf(s2, f0, sv0); sv1 = fmaf(s2, f1, sv1);
    sv2 = fmaf(s2, f2, sv2); sv3 = fmaf(s2, f3, sv3);
    mv0 = fmaxf(mv0, s2 * f0); mv1 = fmaxf(mv1, s2 * f1);
    mv2 = fmaxf(mv2, s2 * f2); mv3 = fmaxf(mv3, s2 * f3);
    f0 = bf2f(g3.x); f1 = bf2f(g3.y); f2 = bf2f(g3.z); f3 = bf2f(g3.w);
    sv0 = fmaf(s3, f0, sv0); sv1 = fmaf(s3, f1, sv1);
    sv2 = fmaf(s3, f2, sv2); sv3 = fmaf(s3, f3, sv3);
    mv0 = fmaxf(mv0, s3 * f0); mv1 = fmaxf(mv1, s3 * f1);
    mv2 = fmaxf(mv2, s3 * f2); mv3 = fmaxf(mv3, s3 * f3);
    sum_s += (s0 + s1) + (s2 + s3);
    mx_s = fmaxf(mx_s, fmaxf(fmaxf(s0, s1), fmaxf(s2, s3)));
    mn_s = fminf(mn_s, fminf(fminf(s0, s1), fminf(s2, s3)));
  }
  for (; j < je; ++j) {                          // tail 0..3
    int o0 = col[j];
    float s0 = sv[j];
    ushort4 g0 = *(const ushort4*)(xp_oth + (size_t)o0 * 256 + 4 * l);
    float f0 = bf2f(g0.x), f1 = bf2f(g0.y), f2 = bf2f(g0.z), f3 = bf2f(g0.w);
    sv0 = fmaf(s0, f0, sv0); sv1 = fmaf(s0, f1, sv1);
    sv2 = fmaf(s0, f2, sv2); sv3 = fmaf(s0, f3, sv3);
    mv0 = fmaxf(mv0, s0 * f0); mv1 = fmaxf(mv1, s0 * f1);
    mv2 = fmaxf(mv2, s0 * f2); mv3 = fmaxf(mv3, s0 * f3);
    sum_s += s0; mx_s = fmaxf(mx_s, s0); mn_s = fminf(mn_s, s0);
  }
  float inv = 1.f / (float)(dg > 0 ? dg : 1);
  float ss = sum_s * inv;
  *(ushort4*)(Hr + 384 + own_off + 4 * l) = make_ushort4(
      f2bf(xp0 * ss), f2bf(xp1 * ss), f2bf(xp2 * ss), f2bf(xp3 * ss));
  *(ushort4*)(Hr + 384 + oth_off + 4 * l) = make_ushort4(
      f2bf(sv0 * inv), f2bf(sv1 * inv), f2bf(sv2 * inv), f2bf(sv3 * inv));
  float a0, a1, a2, a3;
  if (dg > 0) {
    a0 = fmaxf(fmaxf(xp0 * mx_s, xp0 * mn_s), 0.f);
    a1 = fmaxf(fmaxf(xp1 * mx_s, xp1 * mn_s), 0.f);
    a2 = fmaxf(fmaxf(xp2 * mx_s, xp2 * mn_s), 0.f);
    a3 = fmaxf(fmaxf(xp3 * mx_s, xp3 * mn_s), 0.f);
  } else {
    a0 = a1 = a2 = a3 = 0.f;
  }
  *(ushort4*)(Hr + 896 + own_off + 4 * l) =
      make_ushort4(f2bf(a0), f2bf(a1), f2bf(a2), f2bf(a3));
  *(ushort4*)(Hr + 896 + oth_off + 4 * l) =
      make_ushort4(f2bf(fmaxf(mv0, 0.f)), f2bf(fmaxf(mv1, 0.f)),
                   f2bf(fmaxf(mv2, 0.f)), f2bf(fmaxf(mv3, 0.f)));
}

// ---- output GEMM: [cnt,1408]bf16 @ Wt[128][1408]bf16 + b, relu -> f32 -----
// 512 thr / 8 waves (2 row x 4 col), tile 64x128, wave 32x32, acc 2x2.
// BK=64 double-buffered via global_load_lds; same swizzle family as before.
__global__ __launch_bounds__(512) void k_gemm_out(
    const unsigned short* __restrict__ H, const unsigned short* __restrict__ Wt,
    const float* __restrict__ bias, float* __restrict__ out, int Nloc) {
  __shared__ unsigned short Ab[2][64 * 64];     //  8 KB x2
  __shared__ unsigned short Bb[2][128 * 64];    // 16 KB x2
  const int tid = threadIdx.x;
  const int l = tid & 63;
  const int lr = l & 15, lg = l >> 4;
  const int w = tid >> 6;                       // 0..7
  const int wr = w >> 2, wc = w & 3;            // 2 x 4 wave grid
  const int r0 = blockIdx.x * 64;
  const int wbase = tid & 448;                  // w*64, wave-uniform

  f32x4 acc[2][2];
#pragma unroll
  for (int m = 0; m < 2; ++m)
#pragma unroll
    for (int t = 0; t < 2; ++t) {
      f32x4 z = {0.f, 0.f, 0.f, 0.f};
      acc[m][t] = z;
    }

  auto stage = [&](int b, int kb) {
    {                                           // A: 64 rows x 8 chunks = 512
      int row = tid >> 3, c = tid & 7;
      int sc = c ^ (row & 7);
      GLD16(H + (size_t)(r0 + row) * 1408 + kb + sc * 8,
            &Ab[b][(size_t)wbase * 8]);
    }
#pragma unroll
    for (int i = 0; i < 2; ++i) {               // B: 128 rows x 8 chunks = 1024
      int g = i * 512 + tid;
      int row = g >> 3, c = g & 7;
      int sc = c ^ (row & 7);
      GLD16(Wt + (size_t)row * 1408 + kb + sc * 8,
            &Bb[b][(size_t)(i * 512 + wbase) * 8]);
    }
  };

  auto compute = [&](int b) {
#pragma unroll
    for (int kk = 0; kk < 2; ++kk) {
      int chq = kk * 4 + lg;
      bf16x8 a[2], bt[2];
#pragma unroll
      for (int m = 0; m < 2; ++m) {
        int row = wr * 32 + m * 16 + lr;
        a[m] = *(const bf16x8*)&Ab[b][(row * 8 + (chq ^ (row & 7))) * 8];
      }
#pragma unroll
      for (int t = 0; t < 2; ++t) {
        int row = wc * 32 + t * 16 + lr;
        bt[t] = *(const bf16x8*)&Bb[b][(row * 8 + (chq ^ (row & 7))) * 8];
      }
#pragma unroll
      for (int m = 0; m < 2; ++m)
#pragma unroll
        for (int t = 0; t < 2; ++t)
          acc[m][t] = __builtin_amdgcn_mfma_f32_16x16x32_bf16(
              a[m], bt[t], acc[m][t], 0, 0, 0);
    }
  };

  stage(0, 0);
  __syncthreads();
  int cur = 0;
  for (int t = 0; t < 22; ++t) {                // 22 * 64 = K = 1408
    if (t < 21) stage(cur ^ 1, (t + 1) * 64);
    compute(cur);
    __syncthreads();
    cur ^= 1;
  }

#pragma unroll
  for (int m = 0; m < 2; ++m) {
    int rb = r0 + wr * 32 + m * 16 + lg * 4;    // C/D: col=lane&15, row=lg*4+reg
#pragma unroll
    for (int t = 0; t < 2; ++t) {
      int c = wc * 32 + t * 16 + lr;
      float bbias = bias[c];
#pragma unroll
      for (int r = 0; r < 4; ++r) {
        int rr = rb + r;
        if (rr < Nloc) out[(size_t)rr * 128 + c] = fmaxf(acc[m][t][r] + bbias, 0.f);
      }
    }
  }
}

extern "C" void kernel_launch(void* const* d_in, const int* in_sizes, int n_in,
                              void* d_out, int out_size, void* d_ws,
                              size_t ws_size, hipStream_t stream) {
  const float* x_i  = (const float*)d_in[0];
  const float* x_m  = (const float*)d_in[1];
  const int*   ei   = (const int*)d_in[2];
  const float* Wi_i = (const float*)d_in[3];
  const float* bi_i = (const float*)d_in[4];
  const float* Wi_m = (const float*)d_in[5];
  const float* bi_m = (const float*)d_in[6];
  const float* Wsc  = (const float*)d_in[7];
  const float* bsc  = (const float*)d_in[8];
  const float* Wo_i = (const float*)d_in[9];
  const float* bo_i = (const float*)d_in[10];
  const float* Wo_m = (const float*)d_in[11];
  const float* bo_m = (const float*)d_in[12];
  float* out = (float*)d_out;

  int Ni = in_sizes[0] / 128, Nm = in_sizes[1] / 128, E = in_sizes[2] / 2;
  const int* es = ei;
  const int* ee = ei + E;
  int nbi = (Ni + 255) / 256, nbm = (Nm + 255) / 256;   // <= 1024 assumed

  char* p = (char*)d_ws;
  auto alloc = [&](size_t bytes) {
    char* q = p;
    p += (bytes + 255) & ~(size_t)255;
    return q;
  };
  unsigned short* xp_i = (unsigned short*)alloc((size_t)Ni * 256 * 2);
  unsigned short* xp_m = (unsigned short*)alloc((size_t)Nm * 256 * 2);
  float* a_i   = (float*)alloc((size_t)Ni * 4);
  float* a_m   = (float*)alloc((size_t)Nm * 4);
  int* deg_i   = (int*)alloc((size_t)Ni * 4);
  int* deg_m   = (int*)alloc((size_t)Nm * 4);
  int* rp_i    = (int*)alloc((size_t)(Ni + 1) * 4);
  int* rp_m    = (int*)alloc((size_t)(Nm + 1) * 4);
  int* cur_i   = (int*)alloc((size_t)Ni * 4);
  int* cur_m   = (int*)alloc((size_t)Nm * 4);
  int* bs_i    = (int*)alloc((size_t)nbi * 4);
  int* bs_m    = (int*)alloc((size_t)nbm * 4);
  int* bb_i    = (int*)alloc((size_t)nbi * 4);
  int* bb_m    = (int*)alloc((size_t)nbm * 4);
  int* col_i   = (int*)alloc((size_t)E * 4);
  int* col_m   = (int*)alloc((size_t)E * 4);
  float* sv_i  = (float*)alloc((size_t)E * 4);
  float* sv_m  = (float*)alloc((size_t)E * 4);
  unsigned short* Wt_i = (unsigned short*)alloc((size_t)128 * 1408 * 2);
  unsigned short* Wt_m = (unsigned short*)alloc((size_t)128 * 1408 * 2);
  unsigned short* Wint_i = (unsigned short*)alloc((size_t)256 * 128 * 2);
  unsigned short* Wint_m = (unsigned short*)alloc((size_t)256 * 128 * 2);

  size_t used = (size_t)(p - (char*)d_ws);
  if (used + 256 > ws_size) return;
  size_t avail = ws_size - used - 256;
  long long srows_ll = (long long)(avail / (1408 * 2));
  int maxN = (Ni > Nm ? Ni : Nm);
  int maxPad = (maxN + 127) & ~127;
  int S = (int)(srows_ll > maxPad ? maxPad : srows_ll);
  S &= ~127;
  if (S < 128) return;
  unsigned short* Hs = (unsigned short*)alloc((size_t)S * 1408 * 2);

  hipMemsetAsync(deg_i, 0, (size_t)Ni * 4, stream);
  hipMemsetAsync(deg_m, 0, (size_t)Nm * 4, stream);
  hipMemsetAsync(a_i, 0, (size_t)Ni * 4, stream);
  hipMemsetAsync(a_m, 0, (size_t)Nm * 4, stream);

  k_prep_wt<<<(1408 * 128 + 255) / 256, 256, 0, stream>>>(Wo_i, Wt_i, 1408, 128);
  k_prep_wt<<<(1408 * 128 + 255) / 256, 256, 0, stream>>>(Wo_m, Wt_m, 1408, 128);
  k_prep_wt<<<(128 * 256 + 255) / 256, 256, 0, stream>>>(Wi_i, Wint_i, 128, 256);
  k_prep_wt<<<(128 * 256 + 255) / 256, 256, 0, stream>>>(Wi_m, Wint_m, 128, 256);

  k_gemm_in<<<(Ni + 63) / 64, 256, 0, stream>>>(x_i, Wint_i, bi_i, Wsc, xp_i, a_i, Ni);
  k_gemm_in<<<(Nm + 63) / 64, 256, 0, stream>>>(x_m, Wint_m, bi_m, Wsc + 256, xp_m, a_m, Nm);

  k_deg<<<(E + 255) / 256, 256, 0, stream>>>(es, ee, E, deg_i, deg_m);
  k_scan_blk<<<nbi, 256, 0, stream>>>(deg_i, bs_i, Ni);
  k_scan_blk<<<nbm, 256, 0, stream>>>(deg_m, bs_m, Nm);
  k_scan_top<<<2, 1024, 0, stream>>>(bs_i, bb_i, nbi, bs_m, bb_m, nbm);
  k_scan_wr<<<nbi, 256, 0, stream>>>(deg_i, bb_i, rp_i, cur_i, Ni, E);
  k_scan_wr<<<nbm, 256, 0, stream>>>(deg_m, bb_m, rp_m, cur_m, Nm, E);
  k_fill<<<(E + 255) / 256, 256, 0, stream>>>(es, ee, E, a_i, a_m, bsc,
                                              cur_i, col_i, sv_i,
                                              cur_m, col_m, sv_m);

  // intt side: own half of pooled cols at [0,256), gathered (mvtx) at [256,512)
  for (int base = 0; base < Ni; base += S) {
    int cnt = Ni - base; if (cnt > S) cnt = S;
    k_agg<<<(cnt + 3) / 4, 256, 0, stream>>>(x_i, xp_i, xp_m, rp_i, col_i,
                                             sv_i, Hs, base, cnt, 0, 256);
    k_gemm_out<<<(cnt + 63) / 64, 512, 0, stream>>>(Hs, Wt_i, bo_i,
                                                    out + (size_t)base * 128, cnt);
  }
  // mvtx side: gathered (intt) at [0,256), own half at [256,512)
  float* out_m = out + (size_t)Ni * 128;
  for (int base = 0; base < Nm; base += S) {
    int cnt = Nm - base; if (cnt > S) cnt = S;
    k_agg<<<(cnt + 3) / 4, 256, 0, stream>>>(x_m, xp_m, xp_i, rp_m, col_m,
                                             sv_m, Hs, base, cnt, 256, 0);
    k_gemm_out<<<(cnt + 63) / 64, 512, 0, stream>>>(Hs, Wt_m, bo_m,
                                                    out_m + (size_t)base * 128, cnt);
  }
}

// Round 14
// 292.096 us; speedup vs baseline: 1.2044x; 1.1441x over previous
//
#include <hip/hip_runtime.h>

// ---------------------------------------------------------------------------
// BipartiteLayer: xp = x@W_in+b ; s = exp(-|[xp_i[s],xp_m[e]]@W_score+b|) ;
// scatter mean/max of xp_pair*s ; h = relu([x,xp,mean,max]@W_out+b)
//
// R14: H de-materialization. H = [x | xp | mean | max] but x,xp are copies
// and own-side mean/max are closed forms of xp and 3 per-node scalars.
// k_agg now writes only the gathered 512 cols (Hg) + scal(ss,mx,mn);
// k_gemm_out stages A per K-step from x (f32 reg-stage), xp (gload_lds),
// own-halves (recompute from xp+scal in regs), Hg (gload_lds).
// Saves ~86 MB write + ~60 MB read per side; all value paths bit-identical.
//
// Pipeline:
//   k_prep_wt / k_gemm_in / k_deg / k_scan_* / k_fill : unchanged from R13
//   per slab: k_agg (gather->Hg+scal) ; k_gemm_out (composite-A MFMA GEMM)
// ---------------------------------------------------------------------------

typedef __attribute__((ext_vector_type(8))) short bf16x8;   // 8 bf16 = 4 VGPR
typedef __attribute__((ext_vector_type(4))) float f32x4;

static __device__ __forceinline__ unsigned short f2bf(float f) {
  unsigned int u = __float_as_uint(f);
  u = (u + 0x7FFFu + ((u >> 16) & 1u)) >> 16;   // RNE
  return (unsigned short)u;
}
static __device__ __forceinline__ float bf2f(unsigned short s) {
  return __uint_as_float(((unsigned int)s) << 16);
}

#define GLD16(gp, lp)                                                        \
  __builtin_amdgcn_global_load_lds(                                          \
      (const __attribute__((address_space(1))) void*)(gp),                   \
      (__attribute__((address_space(3))) void*)(lp), 16, 0, 0)

// ---- transpose W (KxNcol f32) -> Wt[col][k] bf16 ---------------------------
__global__ void k_prep_wt(const float* __restrict__ Wo,
                          unsigned short* __restrict__ Wt, int K, int Ncol) {
  int idx = blockIdx.x * blockDim.x + threadIdx.x;
  if (idx >= K * Ncol) return;
  int k = idx / Ncol, c = idx % Ncol;
  Wt[(size_t)c * K + k] = f2bf(Wo[idx]);
}

// ---- input GEMM (MFMA): [N,128]f32 @ [128,256] -> xp bf16, a=xp.Ws --------
__global__ __launch_bounds__(256) void k_gemm_in(
    const float* __restrict__ x, const unsigned short* __restrict__ Wint,
    const float* __restrict__ bias, const float* __restrict__ Wsc,
    unsigned short* __restrict__ xp, float* __restrict__ a_out, int N) {
  __shared__ __align__(16) unsigned short Ab[64 * 16 * 8];    // 16 KB
  __shared__ __align__(16) unsigned short Bb[256 * 16 * 8];   // 64 KB
  const int tid = threadIdx.x;
  const int l = tid & 63;
  const int lr = l & 15, lg = l >> 4;
  const int w = tid >> 6, wr = w >> 1, wc = w & 1;
  const int r0 = blockIdx.x * 64;
  const int wbase = tid & 192;                  // w*64, wave-uniform

#pragma unroll
  for (int i = 0; i < 16; ++i) {                // B: 256 rows x 16 chunks
    int g = i * 256 + tid;
    int row = g >> 4, c = g & 15;
    int sc = c ^ (row & 7);
    GLD16(Wint + (size_t)row * 128 + sc * 8,
          &Bb[(size_t)(i * 256 + wbase) * 8]);
  }
#pragma unroll
  for (int i = 0; i < 4; ++i) {                 // A: reg-stage f32->bf16
    int g = i * 256 + tid;
    int row = g >> 4, c = g & 15;
    int ar = min(r0 + row, N - 1);
    const float* src = x + (size_t)ar * 128 + c * 8;
    float4 u = *(const float4*)src;
    float4 v = *(const float4*)(src + 4);
    bf16x8 h;
    h[0] = (short)f2bf(u.x); h[1] = (short)f2bf(u.y);
    h[2] = (short)f2bf(u.z); h[3] = (short)f2bf(u.w);
    h[4] = (short)f2bf(v.x); h[5] = (short)f2bf(v.y);
    h[6] = (short)f2bf(v.z); h[7] = (short)f2bf(v.w);
    *(bf16x8*)&Ab[(size_t)(row * 16 + (c ^ (row & 7))) * 8] = h;
  }
  __syncthreads();

  f32x4 acc[2][8];
#pragma unroll
  for (int m = 0; m < 2; ++m)
#pragma unroll
    for (int t = 0; t < 8; ++t) {
      f32x4 z = {0.f, 0.f, 0.f, 0.f};
      acc[m][t] = z;
    }
#pragma unroll
  for (int kk = 0; kk < 4; ++kk) {
    int chq = kk * 4 + lg;
    bf16x8 a[2], bt[8];
#pragma unroll
    for (int m = 0; m < 2; ++m) {
      int row = wr * 32 + m * 16 + lr;
      a[m] = *(const bf16x8*)&Ab[(row * 16 + (chq ^ (row & 7))) * 8];
    }
#pragma unroll
    for (int t = 0; t < 8; ++t) {
      int row = wc * 128 + t * 16 + lr;
      bt[t] = *(const bf16x8*)&Bb[(row * 16 + (chq ^ (row & 7))) * 8];
    }
#pragma unroll
    for (int m = 0; m < 2; ++m)
#pragma unroll
      for (int t = 0; t < 8; ++t)
        acc[m][t] = __builtin_amdgcn_mfma_f32_16x16x32_bf16(
            a[m], bt[t], acc[m][t], 0, 0, 0);
  }

  float wscv[8], bb[8];
#pragma unroll
  for (int t = 0; t < 8; ++t) {
    int c = wc * 128 + t * 16 + lr;
    wscv[t] = Wsc[c];
    bb[t] = bias[c];
  }
#pragma unroll
  for (int m = 0; m < 2; ++m) {
    int rb = r0 + wr * 32 + m * 16 + lg * 4;    // C/D: col=lane&15, row=lg*4+reg
    float p0 = 0.f, p1 = 0.f, p2 = 0.f, p3 = 0.f;
#pragma unroll
    for (int t = 0; t < 8; ++t) {
      int c = wc * 128 + t * 16 + lr;
      float v0 = acc[m][t][0] + bb[t];
      float v1 = acc[m][t][1] + bb[t];
      float v2 = acc[m][t][2] + bb[t];
      float v3 = acc[m][t][3] + bb[t];
      if (rb + 0 < N) xp[(size_t)(rb + 0) * 256 + c] = f2bf(v0);
      if (rb + 1 < N) xp[(size_t)(rb + 1) * 256 + c] = f2bf(v1);
      if (rb + 2 < N) xp[(size_t)(rb + 2) * 256 + c] = f2bf(v2);
      if (rb + 3 < N) xp[(size_t)(rb + 3) * 256 + c] = f2bf(v3);
      p0 = fmaf(v0, wscv[t], p0); p1 = fmaf(v1, wscv[t], p1);
      p2 = fmaf(v2, wscv[t], p2); p3 = fmaf(v3, wscv[t], p3);
    }
#pragma unroll
    for (int off = 1; off < 16; off <<= 1) {
      p0 += __shfl_xor(p0, off); p1 += __shfl_xor(p1, off);
      p2 += __shfl_xor(p2, off); p3 += __shfl_xor(p3, off);
    }
    if (lr == 0) {
      if (rb + 0 < N) atomicAdd(a_out + rb + 0, p0);
      if (rb + 1 < N) atomicAdd(a_out + rb + 1, p1);
      if (rb + 2 < N) atomicAdd(a_out + rb + 2, p2);
      if (rb + 3 < N) atomicAdd(a_out + rb + 3, p3);
    }
  }
}

// ---- CSR build: degree histogram ------------------------------------------
__global__ void k_deg(const int* __restrict__ es, const int* __restrict__ ee,
                      int E, int* __restrict__ deg_i, int* __restrict__ deg_m) {
  int e = blockIdx.x * blockDim.x + threadIdx.x;
  if (e >= E) return;
  atomicAdd(deg_i + es[e], 1);
  atomicAdd(deg_m + ee[e], 1);
}

// ---- CSR scan phase 1: per-block (256 nodes) degree sum --------------------
__global__ __launch_bounds__(256) void k_scan_blk(
    const int* __restrict__ deg, int* __restrict__ blksum, int n) {
  __shared__ int sm[256];
  int t = threadIdx.x;
  int i = blockIdx.x * 256 + t;
  sm[t] = (i < n) ? deg[i] : 0;
  __syncthreads();
#pragma unroll
  for (int off = 128; off; off >>= 1) {
    if (t < off) sm[t] += sm[t + off];
    __syncthreads();
  }
  if (t == 0) blksum[blockIdx.x] = sm[0];
}

// ---- CSR scan phase 2: exclusive scan of block sums (<=1024 blocks/side) --
__global__ __launch_bounds__(1024) void k_scan_top(
    const int* __restrict__ bs_i, int* __restrict__ bb_i, int nbi,
    const int* __restrict__ bs_m, int* __restrict__ bb_m, int nbm) {
  const int* bs = blockIdx.x ? bs_m : bs_i;
  int* bb = blockIdx.x ? bb_m : bb_i;
  int nb = blockIdx.x ? nbm : nbi;
  __shared__ int sm[1024];
  int t = threadIdx.x;
  int d = (t < nb) ? bs[t] : 0;
  sm[t] = d;
  __syncthreads();
  for (int off = 1; off < 1024; off <<= 1) {    // Hillis-Steele inclusive
    int v = (t >= off) ? sm[t - off] : 0;
    __syncthreads();
    sm[t] += v;
    __syncthreads();
  }
  if (t < nb) bb[t] = sm[t] - d;                // exclusive
}

// ---- CSR scan phase 3: per-block exclusive scan + base -> rp, cur ---------
__global__ __launch_bounds__(256) void k_scan_wr(
    const int* __restrict__ deg, const int* __restrict__ blkbase,
    int* __restrict__ rp, int* __restrict__ cur, int n, int E) {
  __shared__ int sm[256];
  int t = threadIdx.x;
  int i = blockIdx.x * 256 + t;
  int d = (i < n) ? deg[i] : 0;
  sm[t] = d;
  __syncthreads();
  for (int off = 1; off < 256; off <<= 1) {     // Hillis-Steele inclusive
    int v = (t >= off) ? sm[t - off] : 0;
    __syncthreads();
    sm[t] += v;
    __syncthreads();
  }
  if (i < n) {
    int v = blkbase[blockIdx.x] + sm[t] - d;    // exclusive + block base
    rp[i] = v; cur[i] = v;
  }
  if (i == 0) rp[n] = E;
}

// ---- CSR build: score + fill ----------------------------------------------
__global__ void k_fill(const int* __restrict__ es, const int* __restrict__ ee,
                       int E, const float* __restrict__ a_i,
                       const float* __restrict__ a_m,
                       const float* __restrict__ bsc,
                       int* __restrict__ cur_i, int* __restrict__ col_i,
                       float* __restrict__ sv_i,
                       int* __restrict__ cur_m, int* __restrict__ col_m,
                       float* __restrict__ sv_m) {
  int e = blockIdx.x * blockDim.x + threadIdx.x;
  if (e >= E) return;
  int s = es[e], m = ee[e];
  float sc = expf(-fabsf(a_i[s] + a_m[m] + bsc[0]));
  int pi = atomicAdd(cur_i + s, 1);
  col_i[pi] = m; sv_i[pi] = sc;
  int pm = atomicAdd(cur_m + m, 1);
  col_m[pm] = s; sv_m[pm] = sc;
}

// ---- wave-per-node CSR aggregation -> Hg (512 gathered cols) + scal --------
// Hg[local] = [mean_oth(256) | max_oth(256)]; scal[local] = (ss, mx, mn, 0).
__global__ __launch_bounds__(256) void k_agg(
    const unsigned short* __restrict__ xp_oth,
    const int* __restrict__ rowptr, const int* __restrict__ col,
    const float* __restrict__ sv, unsigned short* __restrict__ Hg,
    float4* __restrict__ scal, int base, int cnt) {
  int local = blockIdx.x * 4 + (threadIdx.x >> 6);
  if (local >= cnt) return;                      // wave-uniform
  int node = base + local;
  int l = threadIdx.x & 63;

  float sum_s = 0.f, mx_s = -1e30f, mn_s = 1e30f;
  float sv0 = 0.f, sv1 = 0.f, sv2 = 0.f, sv3 = 0.f;
  float mv0 = -1e30f, mv1 = -1e30f, mv2 = -1e30f, mv3 = -1e30f;
  int jb = rowptr[node], je = rowptr[node + 1];
  int dg = je - jb;
  int j = jb;
  for (; j + 3 < je; j += 4) {                   // 4 independent gathers
    int o0 = col[j], o1 = col[j + 1], o2 = col[j + 2], o3 = col[j + 3];
    float s0 = sv[j], s1 = sv[j + 1], s2 = sv[j + 2], s3 = sv[j + 3];
    ushort4 g0 = *(const ushort4*)(xp_oth + (size_t)o0 * 256 + 4 * l);
    ushort4 g1 = *(const ushort4*)(xp_oth + (size_t)o1 * 256 + 4 * l);
    ushort4 g2 = *(const ushort4*)(xp_oth + (size_t)o2 * 256 + 4 * l);
    ushort4 g3 = *(const ushort4*)(xp_oth + (size_t)o3 * 256 + 4 * l);
    float f0, f1, f2, f3;
    f0 = bf2f(g0.x); f1 = bf2f(g0.y); f2 = bf2f(g0.z); f3 = bf2f(g0.w);
    sv0 = fmaf(s0, f0, sv0); sv1 = fmaf(s0, f1, sv1);
    sv2 = fmaf(s0, f2, sv2); sv3 = fmaf(s0, f3, sv3);
    mv0 = fmaxf(mv0, s0 * f0); mv1 = fmaxf(mv1, s0 * f1);
    mv2 = fmaxf(mv2, s0 * f2); mv3 = fmaxf(mv3, s0 * f3);
    f0 = bf2f(g1.x); f1 = bf2f(g1.y); f2 = bf2f(g1.z); f3 = bf2f(g1.w);
    sv0 = fmaf(s1, f0, sv0); sv1 = fmaf(s1, f1, sv1);
    sv2 = fmaf(s1, f2, sv2); sv3 = fmaf(s1, f3, sv3);
    mv0 = fmaxf(mv0, s1 * f0); mv1 = fmaxf(mv1, s1 * f1);
    mv2 = fmaxf(mv2, s1 * f2); mv3 = fmaxf(mv3, s1 * f3);
    f0 = bf2f(g2.x); f1 = bf2f(g2.y); f2 = bf2f(g2.z); f3 = bf2f(g2.w);
    sv0 = fmaf(s2, f0, sv0); sv1 = fmaf(s2, f1, sv1);
    sv2 = fmaf(s2, f2, sv2); sv3 = fmaf(s2, f3, sv3);
    mv0 = fmaxf(mv0, s2 * f0); mv1 = fmaxf(mv1, s2 * f1);
    mv2 = fmaxf(mv2, s2 * f2); mv3 = fmaxf(mv3, s2 * f3);
    f0 = bf2f(g3.x); f1 = bf2f(g3.y); f2 = bf2f(g3.z); f3 = bf2f(g3.w);
    sv0 = fmaf(s3, f0, sv0); sv1 = fmaf(s3, f1, sv1);
    sv2 = fmaf(s3, f2, sv2); sv3 = fmaf(s3, f3, sv3);
    mv0 = fmaxf(mv0, s3 * f0); mv1 = fmaxf(mv1, s3 * f1);
    mv2 = fmaxf(mv2, s3 * f2); mv3 = fmaxf(mv3, s3 * f3);
    sum_s += (s0 + s1) + (s2 + s3);
    mx_s = fmaxf(mx_s, fmaxf(fmaxf(s0, s1), fmaxf(s2, s3)));
    mn_s = fminf(mn_s, fminf(fminf(s0, s1), fminf(s2, s3)));
  }
  for (; j < je; ++j) {                          // tail 0..3
    int o0 = col[j];
    float s0 = sv[j];
    ushort4 g0 = *(const ushort4*)(xp_oth + (size_t)o0 * 256 + 4 * l);
    float f0 = bf2f(g0.x), f1 = bf2f(g0.y), f2 = bf2f(g0.z), f3 = bf2f(g0.w);
    sv0 = fmaf(s0, f0, sv0); sv1 = fmaf(s0, f1, sv1);
    sv2 = fmaf(s0, f2, sv2); sv3 = fmaf(s0, f3, sv3);
    mv0 = fmaxf(mv0, s0 * f0); mv1 = fmaxf(mv1, s0 * f1);
    mv2 = fmaxf(mv2, s0 * f2); mv3 = fmaxf(mv3, s0 * f3);
    sum_s += s0; mx_s = fmaxf(mx_s, s0); mn_s = fminf(mn_s, s0);
  }
  float inv = 1.f / (float)(dg > 0 ? dg : 1);
  unsigned short* Hr = Hg + (size_t)local * 512;
  *(ushort4*)(Hr + 4 * l) = make_ushort4(
      f2bf(sv0 * inv), f2bf(sv1 * inv), f2bf(sv2 * inv), f2bf(sv3 * inv));
  *(ushort4*)(Hr + 256 + 4 * l) = make_ushort4(
      f2bf(fmaxf(mv0, 0.f)), f2bf(fmaxf(mv1, 0.f)),
      f2bf(fmaxf(mv2, 0.f)), f2bf(fmaxf(mv3, 0.f)));
  if (l == 0)
    scal[local] = make_float4(sum_s * inv, dg > 0 ? mx_s : 0.f,
                              dg > 0 ? mn_s : 0.f, 0.f);
}

// ---- output GEMM with composite A -----------------------------------------
// 512 thr / 8 waves (2x4), tile 64x128, wave 32x32. A per K-step t:
//   t 0-1 : x (f32 -> bf16, reg-stage, swizzled ds_write)
//   t 2-5 : xp (global_load_lds, pre-swizzled source)
//   t 6-21: phase=(t-6)>>2, sub=(t-6)&3
//           own phases: recompute from xp + scal (ss | mx,mn clamp), reg-stage
//           oth phases: Hg via global_load_lds
// own_first=1: own at phases 0,2 (intt); 0: own at phases 1,3 (mvtx).
__global__ __launch_bounds__(512) void k_gemm_out(
    const float* __restrict__ x, const unsigned short* __restrict__ xp,
    const unsigned short* __restrict__ Hg, const float4* __restrict__ scal,
    const unsigned short* __restrict__ Wt, const float* __restrict__ bias,
    float* __restrict__ out, int Nloc, int own_first) {
  __shared__ unsigned short Ab[2][64 * 64];     //  8 KB x2
  __shared__ unsigned short Bb[2][128 * 64];    // 16 KB x2
  const int tid = threadIdx.x;
  const int l = tid & 63;
  const int lr = l & 15, lg = l >> 4;
  const int w = tid >> 6;                       // 0..7
  const int wr = w >> 2, wc = w & 3;            // 2 x 4 wave grid
  const int r0 = blockIdx.x * 64;
  const int wbase = tid & 448;                  // w*64, wave-uniform

  // this thread's fixed A-staging coordinates
  const int arow = tid >> 3, ac = tid & 7;
  const int ar = min(r0 + arow, Nloc - 1);
  const int asc = ac ^ (arow & 7);
  unsigned short* adst_reg = &Ab[0][(size_t)(arow * 8 + asc) * 8];
  const size_t adst_off = (size_t)(arow * 8 + asc) * 8;   // same both buffers
  float4 s4 = scal[ar];                          // ss, mx, mn
  const float ss = s4.x, mxs = s4.y, mns = s4.z;

  f32x4 acc[2][2];
#pragma unroll
  for (int m = 0; m < 2; ++m)
#pragma unroll
    for (int t = 0; t < 2; ++t) {
      f32x4 z = {0.f, 0.f, 0.f, 0.f};
      acc[m][t] = z;
    }

  auto stage = [&](int b, int t) {
    // ---- A (64 rows x 64 cols) ----
    if (t < 2) {                                 // x region: f32 reg-stage
      const float* src = x + (size_t)ar * 128 + t * 64 + ac * 8;
      float4 u = *(const float4*)src;
      float4 v = *(const float4*)(src + 4);
      bf16x8 h;
      h[0] = (short)f2bf(u.x); h[1] = (short)f2bf(u.y);
      h[2] = (short)f2bf(u.z); h[3] = (short)f2bf(u.w);
      h[4] = (short)f2bf(v.x); h[5] = (short)f2bf(v.y);
      h[6] = (short)f2bf(v.z); h[7] = (short)f2bf(v.w);
      *(bf16x8*)&Ab[b][adst_off] = h;
    } else if (t < 6) {                          // xp region: direct gload_lds
      GLD16(xp + (size_t)ar * 256 + (t - 2) * 64 + asc * 8,
            &Ab[b][(size_t)wbase * 8]);
    } else {
      int phase = (t - 6) >> 2, sub = (t - 6) & 3;
      int is_own = own_first ? !(phase & 1) : (phase & 1);
      if (is_own) {                              // recompute from xp + scal
        bf16x8 v = *(const bf16x8*)(xp + (size_t)ar * 256 + sub * 64 + ac * 8);
        bf16x8 h;
        if (phase < 2) {                         // own-mean = ss * xp
#pragma unroll
          for (int i = 0; i < 8; ++i)
            h[i] = (short)f2bf(bf2f((unsigned short)v[i]) * ss);
        } else {                                 // own-max = clamp form
#pragma unroll
          for (int i = 0; i < 8; ++i) {
            float f = bf2f((unsigned short)v[i]);
            h[i] = (short)f2bf(fmaxf(fmaxf(f * mxs, f * mns), 0.f));
          }
        }
        *(bf16x8*)&Ab[b][adst_off] = h;
      } else {                                   // gathered half from Hg
        int hoff = (phase >= 2 ? 256 : 0) + sub * 64;
        GLD16(Hg + (size_t)ar * 512 + hoff + asc * 8,
              &Ab[b][(size_t)wbase * 8]);
      }
    }
    // ---- B (128 rows x 64 cols) ----
    int kb = t * 64;
#pragma unroll
    for (int i = 0; i < 2; ++i) {
      int g = i * 512 + tid;
      int row = g >> 3, c = g & 7;
      int sc = c ^ (row & 7);
      GLD16(Wt + (size_t)row * 1408 + kb + sc * 8,
            &Bb[b][(size_t)(i * 512 + wbase) * 8]);
    }
  };

  auto compute = [&](int b) {
#pragma unroll
    for (int kk = 0; kk < 2; ++kk) {
      int chq = kk * 4 + lg;
      bf16x8 a[2], bt[2];
#pragma unroll
      for (int m = 0; m < 2; ++m) {
        int row = wr * 32 + m * 16 + lr;
        a[m] = *(const bf16x8*)&Ab[b][(row * 8 + (chq ^ (row & 7))) * 8];
      }
#pragma unroll
      for (int t = 0; t < 2; ++t) {
        int row = wc * 32 + t * 16 + lr;
        bt[t] = *(const bf16x8*)&Bb[b][(row * 8 + (chq ^ (row & 7))) * 8];
      }
#pragma unroll
      for (int m = 0; m < 2; ++m)
#pragma unroll
        for (int t = 0; t < 2; ++t)
          acc[m][t] = __builtin_amdgcn_mfma_f32_16x16x32_bf16(
              a[m], bt[t], acc[m][t], 0, 0, 0);
    }
  };

  stage(0, 0);
  __syncthreads();
  int cur = 0;
  for (int t = 0; t < 22; ++t) {                // 22 * 64 = K = 1408
    if (t < 21) stage(cur ^ 1, t + 1);
    compute(cur);
    __syncthreads();
    cur ^= 1;
  }

#pragma unroll
  for (int m = 0; m < 2; ++m) {
    int rb = r0 + wr * 32 + m * 16 + lg * 4;    // C/D: col=lane&15, row=lg*4+reg
#pragma unroll
    for (int t = 0; t < 2; ++t) {
      int c = wc * 32 + t * 16 + lr;
      float bbias = bias[c];
#pragma unroll
      for (int r = 0; r < 4; ++r) {
        int rr = rb + r;
        if (rr < Nloc) out[(size_t)rr * 128 + c] = fmaxf(acc[m][t][r] + bbias, 0.f);
      }
    }
  }
}

extern "C" void kernel_launch(void* const* d_in, const int* in_sizes, int n_in,
                              void* d_out, int out_size, void* d_ws,
                              size_t ws_size, hipStream_t stream) {
  const float* x_i  = (const float*)d_in[0];
  const float* x_m  = (const float*)d_in[1];
  const int*   ei   = (const int*)d_in[2];
  const float* Wi_i = (const float*)d_in[3];
  const float* bi_i = (const float*)d_in[4];
  const float* Wi_m = (const float*)d_in[5];
  const float* bi_m = (const float*)d_in[6];
  const float* Wsc  = (const float*)d_in[7];
  const float* bsc  = (const float*)d_in[8];
  const float* Wo_i = (const float*)d_in[9];
  const float* bo_i = (const float*)d_in[10];
  const float* Wo_m = (const float*)d_in[11];
  const float* bo_m = (const float*)d_in[12];
  float* out = (float*)d_out;

  int Ni = in_sizes[0] / 128, Nm = in_sizes[1] / 128, E = in_sizes[2] / 2;
  const int* es = ei;
  const int* ee = ei + E;
  int nbi = (Ni + 255) / 256, nbm = (Nm + 255) / 256;   // <= 1024 assumed

  char* p = (char*)d_ws;
  auto alloc = [&](size_t bytes) {
    char* q = p;
    p += (bytes + 255) & ~(size_t)255;
    return q;
  };
  unsigned short* xp_i = (unsigned short*)alloc((size_t)Ni * 256 * 2);
  unsigned short* xp_m = (unsigned short*)alloc((size_t)Nm * 256 * 2);
  float* a_i   = (float*)alloc((size_t)Ni * 4);
  float* a_m   = (float*)alloc((size_t)Nm * 4);
  int* deg_i   = (int*)alloc((size_t)Ni * 4);
  int* deg_m   = (int*)alloc((size_t)Nm * 4);
  int* rp_i    = (int*)alloc((size_t)(Ni + 1) * 4);
  int* rp_m    = (int*)alloc((size_t)(Nm + 1) * 4);
  int* cur_i   = (int*)alloc((size_t)Ni * 4);
  int* cur_m   = (int*)alloc((size_t)Nm * 4);
  int* bs_i    = (int*)alloc((size_t)nbi * 4);
  int* bs_m    = (int*)alloc((size_t)nbm * 4);
  int* bb_i    = (int*)alloc((size_t)nbi * 4);
  int* bb_m    = (int*)alloc((size_t)nbm * 4);
  int* col_i   = (int*)alloc((size_t)E * 4);
  int* col_m   = (int*)alloc((size_t)E * 4);
  float* sv_i  = (float*)alloc((size_t)E * 4);
  float* sv_m  = (float*)alloc((size_t)E * 4);
  unsigned short* Wt_i = (unsigned short*)alloc((size_t)128 * 1408 * 2);
  unsigned short* Wt_m = (unsigned short*)alloc((size_t)128 * 1408 * 2);
  unsigned short* Wint_i = (unsigned short*)alloc((size_t)256 * 128 * 2);
  unsigned short* Wint_m = (unsigned short*)alloc((size_t)256 * 128 * 2);

  size_t used = (size_t)(p - (char*)d_ws);
  if (used + 256 > ws_size) return;
  size_t avail = ws_size - used - 256;
  // slab rows cost: 512 bf16 (Hg) + float4 (scal) = 1040 B
  long long srows_ll = (long long)(avail / 1040);
  int maxN = (Ni > Nm ? Ni : Nm);
  int maxPad = (maxN + 127) & ~127;
  int S = (int)(srows_ll > maxPad ? maxPad : srows_ll);
  S &= ~127;
  if (S < 128) return;
  unsigned short* Hg = (unsigned short*)alloc((size_t)S * 512 * 2);
  float4* scal = (float4*)alloc((size_t)S * 16);

  hipMemsetAsync(deg_i, 0, (size_t)Ni * 4, stream);
  hipMemsetAsync(deg_m, 0, (size_t)Nm * 4, stream);
  hipMemsetAsync(a_i, 0, (size_t)Ni * 4, stream);
  hipMemsetAsync(a_m, 0, (size_t)Nm * 4, stream);

  k_prep_wt<<<(1408 * 128 + 255) / 256, 256, 0, stream>>>(Wo_i, Wt_i, 1408, 128);
  k_prep_wt<<<(1408 * 128 + 255) / 256, 256, 0, stream>>>(Wo_m, Wt_m, 1408, 128);
  k_prep_wt<<<(128 * 256 + 255) / 256, 256, 0, stream>>>(Wi_i, Wint_i, 128, 256);
  k_prep_wt<<<(128 * 256 + 255) / 256, 256, 0, stream>>>(Wi_m, Wint_m, 128, 256);

  k_gemm_in<<<(Ni + 63) / 64, 256, 0, stream>>>(x_i, Wint_i, bi_i, Wsc, xp_i, a_i, Ni);
  k_gemm_in<<<(Nm + 63) / 64, 256, 0, stream>>>(x_m, Wint_m, bi_m, Wsc + 256, xp_m, a_m, Nm);

  k_deg<<<(E + 255) / 256, 256, 0, stream>>>(es, ee, E, deg_i, deg_m);
  k_scan_blk<<<nbi, 256, 0, stream>>>(deg_i, bs_i, Ni);
  k_scan_blk<<<nbm, 256, 0, stream>>>(deg_m, bs_m, Nm);
  k_scan_top<<<2, 1024, 0, stream>>>(bs_i, bb_i, nbi, bs_m, bb_m, nbm);
  k_scan_wr<<<nbi, 256, 0, stream>>>(deg_i, bb_i, rp_i, cur_i, Ni, E);
  k_scan_wr<<<nbm, 256, 0, stream>>>(deg_m, bb_m, rp_m, cur_m, Nm, E);
  k_fill<<<(E + 255) / 256, 256, 0, stream>>>(es, ee, E, a_i, a_m, bsc,
                                              cur_i, col_i, sv_i,
                                              cur_m, col_m, sv_m);

  // intt side: own halves first in pooled blocks (own_first=1)
  for (int base = 0; base < Ni; base += S) {
    int cnt = Ni - base; if (cnt > S) cnt = S;
    k_agg<<<(cnt + 3) / 4, 256, 0, stream>>>(xp_m, rp_i, col_i, sv_i,
                                             Hg, scal, base, cnt);
    k_gemm_out<<<(cnt + 63) / 64, 512, 0, stream>>>(
        x_i + (size_t)base * 128, xp_i + (size_t)base * 256, Hg, scal,
        Wt_i, bo_i, out + (size_t)base * 128, cnt, 1);
  }
  // mvtx side: gathered halves first (own_first=0)
  float* out_m = out + (size_t)Ni * 128;
  for (int base = 0; base < Nm; base += S) {
    int cnt = Nm - base; if (cnt > S) cnt = S;
    k_agg<<<(cnt + 3) / 4, 256, 0, stream>>>(xp_i, rp_m, col_m, sv_m,
                                             Hg, scal, base, cnt);
    k_gemm_out<<<(cnt + 63) / 64, 512, 0, stream>>>(
        x_m + (size_t)base * 128, xp_m + (size_t)base * 256, Hg, scal,
        Wt_m, bo_m, out_m + (size_t)base * 128, cnt, 0);
  }
}

// Round 15
// 288.589 us; speedup vs baseline: 1.2191x; 1.0122x over previous
//
#include <hip/hip_runtime.h>

// ---------------------------------------------------------------------------
// BipartiteLayer: xp = x@W_in+b ; s = exp(-|[xp_i[s],xp_m[e]]@W_score+b|) ;
// scatter mean/max of xp_pair*s ; h = relu([x,xp,mean,max]@W_out+b)
//
// R15: slab software-pipeline. agg(slab k+1) is independent of gemm(slab k),
// so run them in ONE block-specialized kernel (low blocks = gemm, rest = agg
// into the other Hg buffer). m114: MFMA-ish and BW-ish waves co-schedule,
// time ~ max not sum. Bodies byte-identical to R14 (passing, absmax 0.0078).
//
// Pipeline:
//   k_prep_wt / k_gemm_in / k_deg / k_scan_* / k_fill : unchanged from R14
//   agg8(slab0) ; for k: fused{ gemm(slab k, buf k&1) || agg(slab k+1, buf ~) }
// ---------------------------------------------------------------------------

typedef __attribute__((ext_vector_type(8))) short bf16x8;   // 8 bf16 = 4 VGPR
typedef __attribute__((ext_vector_type(4))) float f32x4;

static __device__ __forceinline__ unsigned short f2bf(float f) {
  unsigned int u = __float_as_uint(f);
  u = (u + 0x7FFFu + ((u >> 16) & 1u)) >> 16;   // RNE
  return (unsigned short)u;
}
static __device__ __forceinline__ float bf2f(unsigned short s) {
  return __uint_as_float(((unsigned int)s) << 16);
}

#define GLD16(gp, lp)                                                        \
  __builtin_amdgcn_global_load_lds(                                          \
      (const __attribute__((address_space(1))) void*)(gp),                   \
      (__attribute__((address_space(3))) void*)(lp), 16, 0, 0)

// ---- transpose W (KxNcol f32) -> Wt[col][k] bf16 ---------------------------
__global__ void k_prep_wt(const float* __restrict__ Wo,
                          unsigned short* __restrict__ Wt, int K, int Ncol) {
  int idx = blockIdx.x * blockDim.x + threadIdx.x;
  if (idx >= K * Ncol) return;
  int k = idx / Ncol, c = idx % Ncol;
  Wt[(size_t)c * K + k] = f2bf(Wo[idx]);
}

// ---- input GEMM (MFMA): [N,128]f32 @ [128,256] -> xp bf16, a=xp.Ws --------
__global__ __launch_bounds__(256) void k_gemm_in(
    const float* __restrict__ x, const unsigned short* __restrict__ Wint,
    const float* __restrict__ bias, const float* __restrict__ Wsc,
    unsigned short* __restrict__ xp, float* __restrict__ a_out, int N) {
  __shared__ __align__(16) unsigned short Ab[64 * 16 * 8];    // 16 KB
  __shared__ __align__(16) unsigned short Bb[256 * 16 * 8];   // 64 KB
  const int tid = threadIdx.x;
  const int l = tid & 63;
  const int lr = l & 15, lg = l >> 4;
  const int w = tid >> 6, wr = w >> 1, wc = w & 1;
  const int r0 = blockIdx.x * 64;
  const int wbase = tid & 192;                  // w*64, wave-uniform

#pragma unroll
  for (int i = 0; i < 16; ++i) {                // B: 256 rows x 16 chunks
    int g = i * 256 + tid;
    int row = g >> 4, c = g & 15;
    int sc = c ^ (row & 7);
    GLD16(Wint + (size_t)row * 128 + sc * 8,
          &Bb[(size_t)(i * 256 + wbase) * 8]);
  }
#pragma unroll
  for (int i = 0; i < 4; ++i) {                 // A: reg-stage f32->bf16
    int g = i * 256 + tid;
    int row = g >> 4, c = g & 15;
    int ar = min(r0 + row, N - 1);
    const float* src = x + (size_t)ar * 128 + c * 8;
    float4 u = *(const float4*)src;
    float4 v = *(const float4*)(src + 4);
    bf16x8 h;
    h[0] = (short)f2bf(u.x); h[1] = (short)f2bf(u.y);
    h[2] = (short)f2bf(u.z); h[3] = (short)f2bf(u.w);
    h[4] = (short)f2bf(v.x); h[5] = (short)f2bf(v.y);
    h[6] = (short)f2bf(v.z); h[7] = (short)f2bf(v.w);
    *(bf16x8*)&Ab[(size_t)(row * 16 + (c ^ (row & 7))) * 8] = h;
  }
  __syncthreads();

  f32x4 acc[2][8];
#pragma unroll
  for (int m = 0; m < 2; ++m)
#pragma unroll
    for (int t = 0; t < 8; ++t) {
      f32x4 z = {0.f, 0.f, 0.f, 0.f};
      acc[m][t] = z;
    }
#pragma unroll
  for (int kk = 0; kk < 4; ++kk) {
    int chq = kk * 4 + lg;
    bf16x8 a[2], bt[8];
#pragma unroll
    for (int m = 0; m < 2; ++m) {
      int row = wr * 32 + m * 16 + lr;
      a[m] = *(const bf16x8*)&Ab[(row * 16 + (chq ^ (row & 7))) * 8];
    }
#pragma unroll
    for (int t = 0; t < 8; ++t) {
      int row = wc * 128 + t * 16 + lr;
      bt[t] = *(const bf16x8*)&Bb[(row * 16 + (chq ^ (row & 7))) * 8];
    }
#pragma unroll
    for (int m = 0; m < 2; ++m)
#pragma unroll
      for (int t = 0; t < 8; ++t)
        acc[m][t] = __builtin_amdgcn_mfma_f32_16x16x32_bf16(
            a[m], bt[t], acc[m][t], 0, 0, 0);
  }

  float wscv[8], bb[8];
#pragma unroll
  for (int t = 0; t < 8; ++t) {
    int c = wc * 128 + t * 16 + lr;
    wscv[t] = Wsc[c];
    bb[t] = bias[c];
  }
#pragma unroll
  for (int m = 0; m < 2; ++m) {
    int rb = r0 + wr * 32 + m * 16 + lg * 4;    // C/D: col=lane&15, row=lg*4+reg
    float p0 = 0.f, p1 = 0.f, p2 = 0.f, p3 = 0.f;
#pragma unroll
    for (int t = 0; t < 8; ++t) {
      int c = wc * 128 + t * 16 + lr;
      float v0 = acc[m][t][0] + bb[t];
      float v1 = acc[m][t][1] + bb[t];
      float v2 = acc[m][t][2] + bb[t];
      float v3 = acc[m][t][3] + bb[t];
      if (rb + 0 < N) xp[(size_t)(rb + 0) * 256 + c] = f2bf(v0);
      if (rb + 1 < N) xp[(size_t)(rb + 1) * 256 + c] = f2bf(v1);
      if (rb + 2 < N) xp[(size_t)(rb + 2) * 256 + c] = f2bf(v2);
      if (rb + 3 < N) xp[(size_t)(rb + 3) * 256 + c] = f2bf(v3);
      p0 = fmaf(v0, wscv[t], p0); p1 = fmaf(v1, wscv[t], p1);
      p2 = fmaf(v2, wscv[t], p2); p3 = fmaf(v3, wscv[t], p3);
    }
#pragma unroll
    for (int off = 1; off < 16; off <<= 1) {
      p0 += __shfl_xor(p0, off); p1 += __shfl_xor(p1, off);
      p2 += __shfl_xor(p2, off); p3 += __shfl_xor(p3, off);
    }
    if (lr == 0) {
      if (rb + 0 < N) atomicAdd(a_out + rb + 0, p0);
      if (rb + 1 < N) atomicAdd(a_out + rb + 1, p1);
      if (rb + 2 < N) atomicAdd(a_out + rb + 2, p2);
      if (rb + 3 < N) atomicAdd(a_out + rb + 3, p3);
    }
  }
}

// ---- CSR build: degree histogram ------------------------------------------
__global__ void k_deg(const int* __restrict__ es, const int* __restrict__ ee,
                      int E, int* __restrict__ deg_i, int* __restrict__ deg_m) {
  int e = blockIdx.x * blockDim.x + threadIdx.x;
  if (e >= E) return;
  atomicAdd(deg_i + es[e], 1);
  atomicAdd(deg_m + ee[e], 1);
}

// ---- CSR scan phase 1 ------------------------------------------------------
__global__ __launch_bounds__(256) void k_scan_blk(
    const int* __restrict__ deg, int* __restrict__ blksum, int n) {
  __shared__ int sm[256];
  int t = threadIdx.x;
  int i = blockIdx.x * 256 + t;
  sm[t] = (i < n) ? deg[i] : 0;
  __syncthreads();
#pragma unroll
  for (int off = 128; off; off >>= 1) {
    if (t < off) sm[t] += sm[t + off];
    __syncthreads();
  }
  if (t == 0) blksum[blockIdx.x] = sm[0];
}

// ---- CSR scan phase 2 ------------------------------------------------------
__global__ __launch_bounds__(1024) void k_scan_top(
    const int* __restrict__ bs_i, int* __restrict__ bb_i, int nbi,
    const int* __restrict__ bs_m, int* __restrict__ bb_m, int nbm) {
  const int* bs = blockIdx.x ? bs_m : bs_i;
  int* bb = blockIdx.x ? bb_m : bb_i;
  int nb = blockIdx.x ? nbm : nbi;
  __shared__ int sm[1024];
  int t = threadIdx.x;
  int d = (t < nb) ? bs[t] : 0;
  sm[t] = d;
  __syncthreads();
  for (int off = 1; off < 1024; off <<= 1) {    // Hillis-Steele inclusive
    int v = (t >= off) ? sm[t - off] : 0;
    __syncthreads();
    sm[t] += v;
    __syncthreads();
  }
  if (t < nb) bb[t] = sm[t] - d;                // exclusive
}

// ---- CSR scan phase 3 ------------------------------------------------------
__global__ __launch_bounds__(256) void k_scan_wr(
    const int* __restrict__ deg, const int* __restrict__ blkbase,
    int* __restrict__ rp, int* __restrict__ cur, int n, int E) {
  __shared__ int sm[256];
  int t = threadIdx.x;
  int i = blockIdx.x * 256 + t;
  int d = (i < n) ? deg[i] : 0;
  sm[t] = d;
  __syncthreads();
  for (int off = 1; off < 256; off <<= 1) {     // Hillis-Steele inclusive
    int v = (t >= off) ? sm[t - off] : 0;
    __syncthreads();
    sm[t] += v;
    __syncthreads();
  }
  if (i < n) {
    int v = blkbase[blockIdx.x] + sm[t] - d;    // exclusive + block base
    rp[i] = v; cur[i] = v;
  }
  if (i == 0) rp[n] = E;
}

// ---- CSR build: score + fill ----------------------------------------------
__global__ void k_fill(const int* __restrict__ es, const int* __restrict__ ee,
                       int E, const float* __restrict__ a_i,
                       const float* __restrict__ a_m,
                       const float* __restrict__ bsc,
                       int* __restrict__ cur_i, int* __restrict__ col_i,
                       float* __restrict__ sv_i,
                       int* __restrict__ cur_m, int* __restrict__ col_m,
                       float* __restrict__ sv_m) {
  int e = blockIdx.x * blockDim.x + threadIdx.x;
  if (e >= E) return;
  int s = es[e], m = ee[e];
  float sc = expf(-fabsf(a_i[s] + a_m[m] + bsc[0]));
  int pi = atomicAdd(cur_i + s, 1);
  col_i[pi] = m; sv_i[pi] = sc;
  int pm = atomicAdd(cur_m + m, 1);
  col_m[pm] = s; sv_m[pm] = sc;
}

// ---- device body: wave-per-node CSR gather -> Hg + scal (8 waves/block) ----
static __device__ __forceinline__ void dev_agg(
    int bid, const unsigned short* __restrict__ xp_oth,
    const int* __restrict__ rowptr, const int* __restrict__ col,
    const float* __restrict__ sv, unsigned short* __restrict__ Hg,
    float4* __restrict__ scal, int base, int cnt) {
  int local = bid * 8 + ((int)threadIdx.x >> 6);
  if (local >= cnt) return;                      // wave-uniform
  int node = base + local;
  int l = threadIdx.x & 63;

  float sum_s = 0.f, mx_s = -1e30f, mn_s = 1e30f;
  float sv0 = 0.f, sv1 = 0.f, sv2 = 0.f, sv3 = 0.f;
  float mv0 = -1e30f, mv1 = -1e30f, mv2 = -1e30f, mv3 = -1e30f;
  int jb = rowptr[node], je = rowptr[node + 1];
  int dg = je - jb;
  int j = jb;
  for (; j + 3 < je; j += 4) {                   // 4 independent gathers
    int o0 = col[j], o1 = col[j + 1], o2 = col[j + 2], o3 = col[j + 3];
    float s0 = sv[j], s1 = sv[j + 1], s2 = sv[j + 2], s3 = sv[j + 3];
    ushort4 g0 = *(const ushort4*)(xp_oth + (size_t)o0 * 256 + 4 * l);
    ushort4 g1 = *(const ushort4*)(xp_oth + (size_t)o1 * 256 + 4 * l);
    ushort4 g2 = *(const ushort4*)(xp_oth + (size_t)o2 * 256 + 4 * l);
    ushort4 g3 = *(const ushort4*)(xp_oth + (size_t)o3 * 256 + 4 * l);
    float f0, f1, f2, f3;
    f0 = bf2f(g0.x); f1 = bf2f(g0.y); f2 = bf2f(g0.z); f3 = bf2f(g0.w);
    sv0 = fmaf(s0, f0, sv0); sv1 = fmaf(s0, f1, sv1);
    sv2 = fmaf(s0, f2, sv2); sv3 = fmaf(s0, f3, sv3);
    mv0 = fmaxf(mv0, s0 * f0); mv1 = fmaxf(mv1, s0 * f1);
    mv2 = fmaxf(mv2, s0 * f2); mv3 = fmaxf(mv3, s0 * f3);
    f0 = bf2f(g1.x); f1 = bf2f(g1.y); f2 = bf2f(g1.z); f3 = bf2f(g1.w);
    sv0 = fmaf(s1, f0, sv0); sv1 = fmaf(s1, f1, sv1);
    sv2 = fmaf(s1, f2, sv2); sv3 = fmaf(s1, f3, sv3);
    mv0 = fmaxf(mv0, s1 * f0); mv1 = fmaxf(mv1, s1 * f1);
    mv2 = fmaxf(mv2, s1 * f2); mv3 = fmaxf(mv3, s1 * f3);
    f0 = bf2f(g2.x); f1 = bf2f(g2.y); f2 = bf2f(g2.z); f3 = bf2f(g2.w);
    sv0 = fmaf(s2, f0, sv0); sv1 = fmaf(s2, f1, sv1);
    sv2 = fmaf(s2, f2, sv2); sv3 = fmaf(s2, f3, sv3);
    mv0 = fmaxf(mv0, s2 * f0); mv1 = fmaxf(mv1, s2 * f1);
    mv2 = fmaxf(mv2, s2 * f2); mv3 = fmaxf(mv3, s2 * f3);
    f0 = bf2f(g3.x); f1 = bf2f(g3.y); f2 = bf2f(g3.z); f3 = bf2f(g3.w);
    sv0 = fmaf(s3, f0, sv0); sv1 = fmaf(s3, f1, sv1);
    sv2 = fmaf(s3, f2, sv2); sv3 = fmaf(s3, f3, sv3);
    mv0 = fmaxf(mv0, s3 * f0); mv1 = fmaxf(mv1, s3 * f1);
    mv2 = fmaxf(mv2, s3 * f2); mv3 = fmaxf(mv3, s3 * f3);
    sum_s += (s0 + s1) + (s2 + s3);
    mx_s = fmaxf(mx_s, fmaxf(fmaxf(s0, s1), fmaxf(s2, s3)));
    mn_s = fminf(mn_s, fminf(fminf(s0, s1), fminf(s2, s3)));
  }
  for (; j < je; ++j) {                          // tail 0..3
    int o0 = col[j];
    float s0 = sv[j];
    ushort4 g0 = *(const ushort4*)(xp_oth + (size_t)o0 * 256 + 4 * l);
    float f0 = bf2f(g0.x), f1 = bf2f(g0.y), f2 = bf2f(g0.z), f3 = bf2f(g0.w);
    sv0 = fmaf(s0, f0, sv0); sv1 = fmaf(s0, f1, sv1);
    sv2 = fmaf(s0, f2, sv2); sv3 = fmaf(s0, f3, sv3);
    mv0 = fmaxf(mv0, s0 * f0); mv1 = fmaxf(mv1, s0 * f1);
    mv2 = fmaxf(mv2, s0 * f2); mv3 = fmaxf(mv3, s0 * f3);
    sum_s += s0; mx_s = fmaxf(mx_s, s0); mn_s = fminf(mn_s, s0);
  }
  float inv = 1.f / (float)(dg > 0 ? dg : 1);
  unsigned short* Hr = Hg + (size_t)local * 512;
  *(ushort4*)(Hr + 4 * l) = make_ushort4(
      f2bf(sv0 * inv), f2bf(sv1 * inv), f2bf(sv2 * inv), f2bf(sv3 * inv));
  *(ushort4*)(Hr + 256 + 4 * l) = make_ushort4(
      f2bf(fmaxf(mv0, 0.f)), f2bf(fmaxf(mv1, 0.f)),
      f2bf(fmaxf(mv2, 0.f)), f2bf(fmaxf(mv3, 0.f)));
  if (l == 0)
    scal[local] = make_float4(sum_s * inv, dg > 0 ? mx_s : 0.f,
                              dg > 0 ? mn_s : 0.f, 0.f);
}

// ---- device body: composite-A output GEMM (identical math to R14) ----------
static __device__ __forceinline__ void dev_gemm(
    int bid, const float* __restrict__ x, const unsigned short* __restrict__ xp,
    const unsigned short* __restrict__ Hg, const float4* __restrict__ scal,
    const unsigned short* __restrict__ Wt, const float* __restrict__ bias,
    float* __restrict__ out, int Nloc, int own_first) {
  __shared__ unsigned short Ab[2][64 * 64];     //  8 KB x2
  __shared__ unsigned short Bb[2][128 * 64];    // 16 KB x2
  const int tid = threadIdx.x;
  const int l = tid & 63;
  const int lr = l & 15, lg = l >> 4;
  const int w = tid >> 6;                       // 0..7
  const int wr = w >> 2, wc = w & 3;            // 2 x 4 wave grid
  const int r0 = bid * 64;
  const int wbase = tid & 448;                  // w*64, wave-uniform

  const int arow = tid >> 3, ac = tid & 7;
  const int ar = min(r0 + arow, Nloc - 1);
  const int asc = ac ^ (arow & 7);
  const size_t adst_off = (size_t)(arow * 8 + asc) * 8;
  float4 s4 = scal[ar];
  const float ss = s4.x, mxs = s4.y, mns = s4.z;

  f32x4 acc[2][2];
#pragma unroll
  for (int m = 0; m < 2; ++m)
#pragma unroll
    for (int t = 0; t < 2; ++t) {
      f32x4 z = {0.f, 0.f, 0.f, 0.f};
      acc[m][t] = z;
    }

  auto stage = [&](int b, int t) {
    if (t < 2) {                                 // x region: f32 reg-stage
      const float* src = x + (size_t)ar * 128 + t * 64 + ac * 8;
      float4 u = *(const float4*)src;
      float4 v = *(const float4*)(src + 4);
      bf16x8 h;
      h[0] = (short)f2bf(u.x); h[1] = (short)f2bf(u.y);
      h[2] = (short)f2bf(u.z); h[3] = (short)f2bf(u.w);
      h[4] = (short)f2bf(v.x); h[5] = (short)f2bf(v.y);
      h[6] = (short)f2bf(v.z); h[7] = (short)f2bf(v.w);
      *(bf16x8*)&Ab[b][adst_off] = h;
    } else if (t < 6) {                          // xp region: direct gload_lds
      GLD16(xp + (size_t)ar * 256 + (t - 2) * 64 + asc * 8,
            &Ab[b][(size_t)wbase * 8]);
    } else {
      int phase = (t - 6) >> 2, sub = (t - 6) & 3;
      int is_own = own_first ? !(phase & 1) : (phase & 1);
      if (is_own) {                              // recompute from xp + scal
        bf16x8 v = *(const bf16x8*)(xp + (size_t)ar * 256 + sub * 64 + ac * 8);
        bf16x8 h;
        if (phase < 2) {
#pragma unroll
          for (int i = 0; i < 8; ++i)
            h[i] = (short)f2bf(bf2f((unsigned short)v[i]) * ss);
        } else {
#pragma unroll
          for (int i = 0; i < 8; ++i) {
            float f = bf2f((unsigned short)v[i]);
            h[i] = (short)f2bf(fmaxf(fmaxf(f * mxs, f * mns), 0.f));
          }
        }
        *(bf16x8*)&Ab[b][adst_off] = h;
      } else {                                   // gathered half from Hg
        int hoff = (phase >= 2 ? 256 : 0) + sub * 64;
        GLD16(Hg + (size_t)ar * 512 + hoff + asc * 8,
              &Ab[b][(size_t)wbase * 8]);
      }
    }
    int kb = t * 64;                             // B (128 rows x 64 cols)
#pragma unroll
    for (int i = 0; i < 2; ++i) {
      int g = i * 512 + tid;
      int row = g >> 3, c = g & 7;
      int sc = c ^ (row & 7);
      GLD16(Wt + (size_t)row * 1408 + kb + sc * 8,
            &Bb[b][(size_t)(i * 512 + wbase) * 8]);
    }
  };

  auto compute = [&](int b) {
#pragma unroll
    for (int kk = 0; kk < 2; ++kk) {
      int chq = kk * 4 + lg;
      bf16x8 a[2], bt[2];
#pragma unroll
      for (int m = 0; m < 2; ++m) {
        int row = wr * 32 + m * 16 + lr;
        a[m] = *(const bf16x8*)&Ab[b][(row * 8 + (chq ^ (row & 7))) * 8];
      }
#pragma unroll
      for (int t = 0; t < 2; ++t) {
        int row = wc * 32 + t * 16 + lr;
        bt[t] = *(const bf16x8*)&Bb[b][(row * 8 + (chq ^ (row & 7))) * 8];
      }
#pragma unroll
      for (int m = 0; m < 2; ++m)
#pragma unroll
        for (int t = 0; t < 2; ++t)
          acc[m][t] = __builtin_amdgcn_mfma_f32_16x16x32_bf16(
              a[m], bt[t], acc[m][t], 0, 0, 0);
    }
  };

  stage(0, 0);
  __syncthreads();
  int cur = 0;
  for (int t = 0; t < 22; ++t) {                // 22 * 64 = K = 1408
    if (t < 21) stage(cur ^ 1, t + 1);
    compute(cur);
    __syncthreads();
    cur ^= 1;
  }

#pragma unroll
  for (int m = 0; m < 2; ++m) {
    int rb = r0 + wr * 32 + m * 16 + lg * 4;    // C/D: col=lane&15, row=lg*4+reg
#pragma unroll
    for (int t = 0; t < 2; ++t) {
      int c = wc * 32 + t * 16 + lr;
      float bbias = bias[c];
#pragma unroll
      for (int r = 0; r < 4; ++r) {
        int rr = rb + r;
        if (rr < Nloc) out[(size_t)rr * 128 + c] = fmaxf(acc[m][t][r] + bbias, 0.f);
      }
    }
  }
}

// ---- standalone agg (prologue slab), 512 thr / 8 waves ---------------------
__global__ __launch_bounds__(512) void k_agg8(
    const unsigned short* __restrict__ xp_oth,
    const int* __restrict__ rowptr, const int* __restrict__ col,
    const float* __restrict__ sv, unsigned short* __restrict__ Hg,
    float4* __restrict__ scal, int base, int cnt) {
  dev_agg(blockIdx.x, xp_oth, rowptr, col, sv, Hg, scal, base, cnt);
}

// ---- fused: blocks [0,ngemm) run gemm(slab k), rest run agg(slab k+1) ------
__global__ __launch_bounds__(512) void k_fused(
    const float* __restrict__ gx, const unsigned short* __restrict__ gxp,
    const unsigned short* __restrict__ gHg, const float4* __restrict__ gscal,
    const unsigned short* __restrict__ gWt, const float* __restrict__ gbias,
    float* __restrict__ gout, int gN, int gown_first, int ngemm,
    const unsigned short* __restrict__ axp, const int* __restrict__ arp,
    const int* __restrict__ acol, const float* __restrict__ asv,
    unsigned short* __restrict__ aHg, float4* __restrict__ ascal,
    int abase, int acnt) {
  if ((int)blockIdx.x < ngemm)
    dev_gemm(blockIdx.x, gx, gxp, gHg, gscal, gWt, gbias, gout, gN, gown_first);
  else
    dev_agg(blockIdx.x - ngemm, axp, arp, acol, asv, aHg, ascal, abase, acnt);
}

extern "C" void kernel_launch(void* const* d_in, const int* in_sizes, int n_in,
                              void* d_out, int out_size, void* d_ws,
                              size_t ws_size, hipStream_t stream) {
  const float* x_i  = (const float*)d_in[0];
  const float* x_m  = (const float*)d_in[1];
  const int*   ei   = (const int*)d_in[2];
  const float* Wi_i = (const float*)d_in[3];
  const float* bi_i = (const float*)d_in[4];
  const float* Wi_m = (const float*)d_in[5];
  const float* bi_m = (const float*)d_in[6];
  const float* Wsc  = (const float*)d_in[7];
  const float* bsc  = (const float*)d_in[8];
  const float* Wo_i = (const float*)d_in[9];
  const float* bo_i = (const float*)d_in[10];
  const float* Wo_m = (const float*)d_in[11];
  const float* bo_m = (const float*)d_in[12];
  float* out = (float*)d_out;

  int Ni = in_sizes[0] / 128, Nm = in_sizes[1] / 128, E = in_sizes[2] / 2;
  const int* es = ei;
  const int* ee = ei + E;
  int nbi = (Ni + 255) / 256, nbm = (Nm + 255) / 256;   // <= 1024 assumed

  char* p = (char*)d_ws;
  auto alloc = [&](size_t bytes) {
    char* q = p;
    p += (bytes + 255) & ~(size_t)255;
    return q;
  };
  unsigned short* xp_i = (unsigned short*)alloc((size_t)Ni * 256 * 2);
  unsigned short* xp_m = (unsigned short*)alloc((size_t)Nm * 256 * 2);
  float* a_i   = (float*)alloc((size_t)Ni * 4);
  float* a_m   = (float*)alloc((size_t)Nm * 4);
  int* deg_i   = (int*)alloc((size_t)Ni * 4);
  int* deg_m   = (int*)alloc((size_t)Nm * 4);
  int* rp_i    = (int*)alloc((size_t)(Ni + 1) * 4);
  int* rp_m    = (int*)alloc((size_t)(Nm + 1) * 4);
  int* cur_i   = (int*)alloc((size_t)Ni * 4);
  int* cur_m   = (int*)alloc((size_t)Nm * 4);
  int* bs_i    = (int*)alloc((size_t)nbi * 4);
  int* bs_m    = (int*)alloc((size_t)nbm * 4);
  int* bb_i    = (int*)alloc((size_t)nbi * 4);
  int* bb_m    = (int*)alloc((size_t)nbm * 4);
  int* col_i   = (int*)alloc((size_t)E * 4);
  int* col_m   = (int*)alloc((size_t)E * 4);
  float* sv_i  = (float*)alloc((size_t)E * 4);
  float* sv_m  = (float*)alloc((size_t)E * 4);
  unsigned short* Wt_i = (unsigned short*)alloc((size_t)128 * 1408 * 2);
  unsigned short* Wt_m = (unsigned short*)alloc((size_t)128 * 1408 * 2);
  unsigned short* Wint_i = (unsigned short*)alloc((size_t)256 * 128 * 2);
  unsigned short* Wint_m = (unsigned short*)alloc((size_t)256 * 128 * 2);

  size_t used = (size_t)(p - (char*)d_ws);
  if (used + 256 > ws_size) return;
  size_t avail = ws_size - used - 256;
  // double-buffered slabs: 2 x (512 bf16 + float4) = 2080 B per row
  long long srows_ll = (long long)(avail / 2080);
  int maxN = (Ni > Nm ? Ni : Nm);
  int maxPad = (maxN + 127) & ~127;
  int S = (int)(srows_ll > maxPad ? maxPad : srows_ll);
  S &= ~127;
  if (S < 128) return;
  unsigned short* HgB[2];
  float4* scB[2];
  HgB[0] = (unsigned short*)alloc((size_t)S * 512 * 2);
  HgB[1] = (unsigned short*)alloc((size_t)S * 512 * 2);
  scB[0] = (float4*)alloc((size_t)S * 16);
  scB[1] = (float4*)alloc((size_t)S * 16);

  hipMemsetAsync(deg_i, 0, (size_t)Ni * 4, stream);
  hipMemsetAsync(deg_m, 0, (size_t)Nm * 4, stream);
  hipMemsetAsync(a_i, 0, (size_t)Ni * 4, stream);
  hipMemsetAsync(a_m, 0, (size_t)Nm * 4, stream);

  k_prep_wt<<<(1408 * 128 + 255) / 256, 256, 0, stream>>>(Wo_i, Wt_i, 1408, 128);
  k_prep_wt<<<(1408 * 128 + 255) / 256, 256, 0, stream>>>(Wo_m, Wt_m, 1408, 128);
  k_prep_wt<<<(128 * 256 + 255) / 256, 256, 0, stream>>>(Wi_i, Wint_i, 128, 256);
  k_prep_wt<<<(128 * 256 + 255) / 256, 256, 0, stream>>>(Wi_m, Wint_m, 128, 256);

  k_gemm_in<<<(Ni + 63) / 64, 256, 0, stream>>>(x_i, Wint_i, bi_i, Wsc, xp_i, a_i, Ni);
  k_gemm_in<<<(Nm + 63) / 64, 256, 0, stream>>>(x_m, Wint_m, bi_m, Wsc + 256, xp_m, a_m, Nm);

  k_deg<<<(E + 255) / 256, 256, 0, stream>>>(es, ee, E, deg_i, deg_m);
  k_scan_blk<<<nbi, 256, 0, stream>>>(deg_i, bs_i, Ni);
  k_scan_blk<<<nbm, 256, 0, stream>>>(deg_m, bs_m, Nm);
  k_scan_top<<<2, 1024, 0, stream>>>(bs_i, bb_i, nbi, bs_m, bb_m, nbm);
  k_scan_wr<<<nbi, 256, 0, stream>>>(deg_i, bb_i, rp_i, cur_i, Ni, E);
  k_scan_wr<<<nbm, 256, 0, stream>>>(deg_m, bb_m, rp_m, cur_m, Nm, E);
  k_fill<<<(E + 255) / 256, 256, 0, stream>>>(es, ee, E, a_i, a_m, bsc,
                                              cur_i, col_i, sv_i,
                                              cur_m, col_m, sv_m);

  // ---- slab list: side 0 (intt) then side 1 (mvtx) ----
  int nsl = 0;
  int sside[64], sbase[64], scnt[64];
  for (int b = 0; b < Ni && nsl < 64; b += S) {
    sside[nsl] = 0; sbase[nsl] = b;
    scnt[nsl] = (Ni - b < S) ? Ni - b : S; ++nsl;
  }
  for (int b = 0; b < Nm && nsl < 64; b += S) {
    sside[nsl] = 1; sbase[nsl] = b;
    scnt[nsl] = (Nm - b < S) ? Nm - b : S; ++nsl;
  }
  // per-side pointer tables
  const unsigned short* aggxp[2] = {xp_m, xp_i};     // gather from other side
  const int* rpT[2] = {rp_i, rp_m};
  const int* colT[2] = {col_i, col_m};
  const float* svT[2] = {sv_i, sv_m};
  const float* xT[2] = {x_i, x_m};
  const unsigned short* xpT[2] = {xp_i, xp_m};
  const unsigned short* WtT[2] = {Wt_i, Wt_m};
  const float* boT[2] = {bo_i, bo_m};
  float* outT[2] = {out, out + (size_t)Ni * 128};
  int ofT[2] = {1, 0};

  // prologue: agg slab 0 into buffer 0
  {
    int sd = sside[0];
    k_agg8<<<(scnt[0] + 7) / 8, 512, 0, stream>>>(
        aggxp[sd], rpT[sd], colT[sd], svT[sd], HgB[0], scB[0],
        sbase[0], scnt[0]);
  }
  // pipeline: fused { gemm(slab k, buf k&1) || agg(slab k+1, buf (k+1)&1) }
  for (int k = 0; k < nsl; ++k) {
    int sd = sside[k], bse = sbase[k], cnt = scnt[k];
    int ngemm = (cnt + 63) / 64;
    int nagg = 0;
    int k1 = k + 1;
    int sd1 = (k1 < nsl) ? sside[k1] : sd;
    int b1 = (k1 < nsl) ? sbase[k1] : 0;
    int c1 = (k1 < nsl) ? scnt[k1] : 0;
    if (k1 < nsl) nagg = (c1 + 7) / 8;
    k_fused<<<ngemm + nagg, 512, 0, stream>>>(
        xT[sd] + (size_t)bse * 128, xpT[sd] + (size_t)bse * 256,
        HgB[k & 1], scB[k & 1], WtT[sd], boT[sd],
        outT[sd] + (size_t)bse * 128, cnt, ofT[sd], ngemm,
        aggxp[sd1], rpT[sd1], colT[sd1], svT[sd1],
        HgB[k1 & 1], scB[k1 & 1], b1, c1);
  }
}

// Round 16
// 275.292 us; speedup vs baseline: 1.2779x; 1.0483x over previous
//
#include <hip/hip_runtime.h>

// ---------------------------------------------------------------------------
// BipartiteLayer: xp = x@W_in+b ; s = exp(-|[xp_i[s],xp_m[e]]@W_score+b|) ;
// scatter mean/max of xp_pair*s ; h = relu([x,xp,mean,max]@W_out+b)
//
// R16: revert R15's fusion (measured wash: +3.5us, degraded agg 4.4->2.9TB/s).
// Back to R14 split pipeline; k_gemm_out tile 64x128 -> 128x128 (8 waves 4x2,
// wave 32x64): 2x MFMA per barrier-drain, same 22 barriers, 64KB LDS.
// All value paths bit-identical to R14 (absmax 0.0078125).
//
// Pipeline:
//   k_prep_wt / k_gemm_in / k_deg / k_scan_* / k_fill : unchanged
//   per slab: k_agg (gather->Hg+scal) ; k_gemm_out (composite-A 128x128 MFMA)
// ---------------------------------------------------------------------------

typedef __attribute__((ext_vector_type(8))) short bf16x8;   // 8 bf16 = 4 VGPR
typedef __attribute__((ext_vector_type(4))) float f32x4;

static __device__ __forceinline__ unsigned short f2bf(float f) {
  unsigned int u = __float_as_uint(f);
  u = (u + 0x7FFFu + ((u >> 16) & 1u)) >> 16;   // RNE
  return (unsigned short)u;
}
static __device__ __forceinline__ float bf2f(unsigned short s) {
  return __uint_as_float(((unsigned int)s) << 16);
}

#define GLD16(gp, lp)                                                        \
  __builtin_amdgcn_global_load_lds(                                          \
      (const __attribute__((address_space(1))) void*)(gp),                   \
      (__attribute__((address_space(3))) void*)(lp), 16, 0, 0)

// ---- transpose W (KxNcol f32) -> Wt[col][k] bf16 ---------------------------
__global__ void k_prep_wt(const float* __restrict__ Wo,
                          unsigned short* __restrict__ Wt, int K, int Ncol) {
  int idx = blockIdx.x * blockDim.x + threadIdx.x;
  if (idx >= K * Ncol) return;
  int k = idx / Ncol, c = idx % Ncol;
  Wt[(size_t)c * K + k] = f2bf(Wo[idx]);
}

// ---- input GEMM (MFMA): [N,128]f32 @ [128,256] -> xp bf16, a=xp.Ws --------
__global__ __launch_bounds__(256) void k_gemm_in(
    const float* __restrict__ x, const unsigned short* __restrict__ Wint,
    const float* __restrict__ bias, const float* __restrict__ Wsc,
    unsigned short* __restrict__ xp, float* __restrict__ a_out, int N) {
  __shared__ __align__(16) unsigned short Ab[64 * 16 * 8];    // 16 KB
  __shared__ __align__(16) unsigned short Bb[256 * 16 * 8];   // 64 KB
  const int tid = threadIdx.x;
  const int l = tid & 63;
  const int lr = l & 15, lg = l >> 4;
  const int w = tid >> 6, wr = w >> 1, wc = w & 1;
  const int r0 = blockIdx.x * 64;
  const int wbase = tid & 192;                  // w*64, wave-uniform

#pragma unroll
  for (int i = 0; i < 16; ++i) {                // B: 256 rows x 16 chunks
    int g = i * 256 + tid;
    int row = g >> 4, c = g & 15;
    int sc = c ^ (row & 7);
    GLD16(Wint + (size_t)row * 128 + sc * 8,
          &Bb[(size_t)(i * 256 + wbase) * 8]);
  }
#pragma unroll
  for (int i = 0; i < 4; ++i) {                 // A: reg-stage f32->bf16
    int g = i * 256 + tid;
    int row = g >> 4, c = g & 15;
    int ar = min(r0 + row, N - 1);
    const float* src = x + (size_t)ar * 128 + c * 8;
    float4 u = *(const float4*)src;
    float4 v = *(const float4*)(src + 4);
    bf16x8 h;
    h[0] = (short)f2bf(u.x); h[1] = (short)f2bf(u.y);
    h[2] = (short)f2bf(u.z); h[3] = (short)f2bf(u.w);
    h[4] = (short)f2bf(v.x); h[5] = (short)f2bf(v.y);
    h[6] = (short)f2bf(v.z); h[7] = (short)f2bf(v.w);
    *(bf16x8*)&Ab[(size_t)(row * 16 + (c ^ (row & 7))) * 8] = h;
  }
  __syncthreads();

  f32x4 acc[2][8];
#pragma unroll
  for (int m = 0; m < 2; ++m)
#pragma unroll
    for (int t = 0; t < 8; ++t) {
      f32x4 z = {0.f, 0.f, 0.f, 0.f};
      acc[m][t] = z;
    }
#pragma unroll
  for (int kk = 0; kk < 4; ++kk) {
    int chq = kk * 4 + lg;
    bf16x8 a[2], bt[8];
#pragma unroll
    for (int m = 0; m < 2; ++m) {
      int row = wr * 32 + m * 16 + lr;
      a[m] = *(const bf16x8*)&Ab[(row * 16 + (chq ^ (row & 7))) * 8];
    }
#pragma unroll
    for (int t = 0; t < 8; ++t) {
      int row = wc * 128 + t * 16 + lr;
      bt[t] = *(const bf16x8*)&Bb[(row * 16 + (chq ^ (row & 7))) * 8];
    }
#pragma unroll
    for (int m = 0; m < 2; ++m)
#pragma unroll
      for (int t = 0; t < 8; ++t)
        acc[m][t] = __builtin_amdgcn_mfma_f32_16x16x32_bf16(
            a[m], bt[t], acc[m][t], 0, 0, 0);
  }

  float wscv[8], bb[8];
#pragma unroll
  for (int t = 0; t < 8; ++t) {
    int c = wc * 128 + t * 16 + lr;
    wscv[t] = Wsc[c];
    bb[t] = bias[c];
  }
#pragma unroll
  for (int m = 0; m < 2; ++m) {
    int rb = r0 + wr * 32 + m * 16 + lg * 4;    // C/D: col=lane&15, row=lg*4+reg
    float p0 = 0.f, p1 = 0.f, p2 = 0.f, p3 = 0.f;
#pragma unroll
    for (int t = 0; t < 8; ++t) {
      int c = wc * 128 + t * 16 + lr;
      float v0 = acc[m][t][0] + bb[t];
      float v1 = acc[m][t][1] + bb[t];
      float v2 = acc[m][t][2] + bb[t];
      float v3 = acc[m][t][3] + bb[t];
      if (rb + 0 < N) xp[(size_t)(rb + 0) * 256 + c] = f2bf(v0);
      if (rb + 1 < N) xp[(size_t)(rb + 1) * 256 + c] = f2bf(v1);
      if (rb + 2 < N) xp[(size_t)(rb + 2) * 256 + c] = f2bf(v2);
      if (rb + 3 < N) xp[(size_t)(rb + 3) * 256 + c] = f2bf(v3);
      p0 = fmaf(v0, wscv[t], p0); p1 = fmaf(v1, wscv[t], p1);
      p2 = fmaf(v2, wscv[t], p2); p3 = fmaf(v3, wscv[t], p3);
    }
#pragma unroll
    for (int off = 1; off < 16; off <<= 1) {
      p0 += __shfl_xor(p0, off); p1 += __shfl_xor(p1, off);
      p2 += __shfl_xor(p2, off); p3 += __shfl_xor(p3, off);
    }
    if (lr == 0) {
      if (rb + 0 < N) atomicAdd(a_out + rb + 0, p0);
      if (rb + 1 < N) atomicAdd(a_out + rb + 1, p1);
      if (rb + 2 < N) atomicAdd(a_out + rb + 2, p2);
      if (rb + 3 < N) atomicAdd(a_out + rb + 3, p3);
    }
  }
}

// ---- CSR build: degree histogram ------------------------------------------
__global__ void k_deg(const int* __restrict__ es, const int* __restrict__ ee,
                      int E, int* __restrict__ deg_i, int* __restrict__ deg_m) {
  int e = blockIdx.x * blockDim.x + threadIdx.x;
  if (e >= E) return;
  atomicAdd(deg_i + es[e], 1);
  atomicAdd(deg_m + ee[e], 1);
}

// ---- CSR scan phase 1 ------------------------------------------------------
__global__ __launch_bounds__(256) void k_scan_blk(
    const int* __restrict__ deg, int* __restrict__ blksum, int n) {
  __shared__ int sm[256];
  int t = threadIdx.x;
  int i = blockIdx.x * 256 + t;
  sm[t] = (i < n) ? deg[i] : 0;
  __syncthreads();
#pragma unroll
  for (int off = 128; off; off >>= 1) {
    if (t < off) sm[t] += sm[t + off];
    __syncthreads();
  }
  if (t == 0) blksum[blockIdx.x] = sm[0];
}

// ---- CSR scan phase 2 ------------------------------------------------------
__global__ __launch_bounds__(1024) void k_scan_top(
    const int* __restrict__ bs_i, int* __restrict__ bb_i, int nbi,
    const int* __restrict__ bs_m, int* __restrict__ bb_m, int nbm) {
  const int* bs = blockIdx.x ? bs_m : bs_i;
  int* bb = blockIdx.x ? bb_m : bb_i;
  int nb = blockIdx.x ? nbm : nbi;
  __shared__ int sm[1024];
  int t = threadIdx.x;
  int d = (t < nb) ? bs[t] : 0;
  sm[t] = d;
  __syncthreads();
  for (int off = 1; off < 1024; off <<= 1) {    // Hillis-Steele inclusive
    int v = (t >= off) ? sm[t - off] : 0;
    __syncthreads();
    sm[t] += v;
    __syncthreads();
  }
  if (t < nb) bb[t] = sm[t] - d;                // exclusive
}

// ---- CSR scan phase 3 ------------------------------------------------------
__global__ __launch_bounds__(256) void k_scan_wr(
    const int* __restrict__ deg, const int* __restrict__ blkbase,
    int* __restrict__ rp, int* __restrict__ cur, int n, int E) {
  __shared__ int sm[256];
  int t = threadIdx.x;
  int i = blockIdx.x * 256 + t;
  int d = (i < n) ? deg[i] : 0;
  sm[t] = d;
  __syncthreads();
  for (int off = 1; off < 256; off <<= 1) {     // Hillis-Steele inclusive
    int v = (t >= off) ? sm[t - off] : 0;
    __syncthreads();
    sm[t] += v;
    __syncthreads();
  }
  if (i < n) {
    int v = blkbase[blockIdx.x] + sm[t] - d;    // exclusive + block base
    rp[i] = v; cur[i] = v;
  }
  if (i == 0) rp[n] = E;
}

// ---- CSR build: score + fill ----------------------------------------------
__global__ void k_fill(const int* __restrict__ es, const int* __restrict__ ee,
                       int E, const float* __restrict__ a_i,
                       const float* __restrict__ a_m,
                       const float* __restrict__ bsc,
                       int* __restrict__ cur_i, int* __restrict__ col_i,
                       float* __restrict__ sv_i,
                       int* __restrict__ cur_m, int* __restrict__ col_m,
                       float* __restrict__ sv_m) {
  int e = blockIdx.x * blockDim.x + threadIdx.x;
  if (e >= E) return;
  int s = es[e], m = ee[e];
  float sc = expf(-fabsf(a_i[s] + a_m[m] + bsc[0]));
  int pi = atomicAdd(cur_i + s, 1);
  col_i[pi] = m; sv_i[pi] = sc;
  int pm = atomicAdd(cur_m + m, 1);
  col_m[pm] = s; sv_m[pm] = sc;
}

// ---- wave-per-node CSR aggregation -> Hg (512 gathered cols) + scal --------
// Hg[local] = [mean_oth(256) | max_oth(256)]; scal[local] = (ss, mx, mn, 0).
__global__ __launch_bounds__(256) void k_agg(
    const unsigned short* __restrict__ xp_oth,
    const int* __restrict__ rowptr, const int* __restrict__ col,
    const float* __restrict__ sv, unsigned short* __restrict__ Hg,
    float4* __restrict__ scal, int base, int cnt) {
  int local = blockIdx.x * 4 + (threadIdx.x >> 6);
  if (local >= cnt) return;                      // wave-uniform
  int node = base + local;
  int l = threadIdx.x & 63;

  float sum_s = 0.f, mx_s = -1e30f, mn_s = 1e30f;
  float sv0 = 0.f, sv1 = 0.f, sv2 = 0.f, sv3 = 0.f;
  float mv0 = -1e30f, mv1 = -1e30f, mv2 = -1e30f, mv3 = -1e30f;
  int jb = rowptr[node], je = rowptr[node + 1];
  int dg = je - jb;
  int j = jb;
  for (; j + 3 < je; j += 4) {                   // 4 independent gathers
    int o0 = col[j], o1 = col[j + 1], o2 = col[j + 2], o3 = col[j + 3];
    float s0 = sv[j], s1 = sv[j + 1], s2 = sv[j + 2], s3 = sv[j + 3];
    ushort4 g0 = *(const ushort4*)(xp_oth + (size_t)o0 * 256 + 4 * l);
    ushort4 g1 = *(const ushort4*)(xp_oth + (size_t)o1 * 256 + 4 * l);
    ushort4 g2 = *(const ushort4*)(xp_oth + (size_t)o2 * 256 + 4 * l);
    ushort4 g3 = *(const ushort4*)(xp_oth + (size_t)o3 * 256 + 4 * l);
    float f0, f1, f2, f3;
    f0 = bf2f(g0.x); f1 = bf2f(g0.y); f2 = bf2f(g0.z); f3 = bf2f(g0.w);
    sv0 = fmaf(s0, f0, sv0); sv1 = fmaf(s0, f1, sv1);
    sv2 = fmaf(s0, f2, sv2); sv3 = fmaf(s0, f3, sv3);
    mv0 = fmaxf(mv0, s0 * f0); mv1 = fmaxf(mv1, s0 * f1);
    mv2 = fmaxf(mv2, s0 * f2); mv3 = fmaxf(mv3, s0 * f3);
    f0 = bf2f(g1.x); f1 = bf2f(g1.y); f2 = bf2f(g1.z); f3 = bf2f(g1.w);
    sv0 = fmaf(s1, f0, sv0); sv1 = fmaf(s1, f1, sv1);
    sv2 = fmaf(s1, f2, sv2); sv3 = fmaf(s1, f3, sv3);
    mv0 = fmaxf(mv0, s1 * f0); mv1 = fmaxf(mv1, s1 * f1);
    mv2 = fmaxf(mv2, s1 * f2); mv3 = fmaxf(mv3, s1 * f3);
    f0 = bf2f(g2.x); f1 = bf2f(g2.y); f2 = bf2f(g2.z); f3 = bf2f(g2.w);
    sv0 = fmaf(s2, f0, sv0); sv1 = fmaf(s2, f1, sv1);
    sv2 = fmaf(s2, f2, sv2); sv3 = fmaf(s2, f3, sv3);
    mv0 = fmaxf(mv0, s2 * f0); mv1 = fmaxf(mv1, s2 * f1);
    mv2 = fmaxf(mv2, s2 * f2); mv3 = fmaxf(mv3, s2 * f3);
    f0 = bf2f(g3.x); f1 = bf2f(g3.y); f2 = bf2f(g3.z); f3 = bf2f(g3.w);
    sv0 = fmaf(s3, f0, sv0); sv1 = fmaf(s3, f1, sv1);
    sv2 = fmaf(s3, f2, sv2); sv3 = fmaf(s3, f3, sv3);
    mv0 = fmaxf(mv0, s3 * f0); mv1 = fmaxf(mv1, s3 * f1);
    mv2 = fmaxf(mv2, s3 * f2); mv3 = fmaxf(mv3, s3 * f3);
    sum_s += (s0 + s1) + (s2 + s3);
    mx_s = fmaxf(mx_s, fmaxf(fmaxf(s0, s1), fmaxf(s2, s3)));
    mn_s = fminf(mn_s, fminf(fminf(s0, s1), fminf(s2, s3)));
  }
  for (; j < je; ++j) {                          // tail 0..3
    int o0 = col[j];
    float s0 = sv[j];
    ushort4 g0 = *(const ushort4*)(xp_oth + (size_t)o0 * 256 + 4 * l);
    float f0 = bf2f(g0.x), f1 = bf2f(g0.y), f2 = bf2f(g0.z), f3 = bf2f(g0.w);
    sv0 = fmaf(s0, f0, sv0); sv1 = fmaf(s0, f1, sv1);
    sv2 = fmaf(s0, f2, sv2); sv3 = fmaf(s0, f3, sv3);
    mv0 = fmaxf(mv0, s0 * f0); mv1 = fmaxf(mv1, s0 * f1);
    mv2 = fmaxf(mv2, s0 * f2); mv3 = fmaxf(mv3, s0 * f3);
    sum_s += s0; mx_s = fmaxf(mx_s, s0); mn_s = fminf(mn_s, s0);
  }
  float inv = 1.f / (float)(dg > 0 ? dg : 1);
  unsigned short* Hr = Hg + (size_t)local * 512;
  *(ushort4*)(Hr + 4 * l) = make_ushort4(
      f2bf(sv0 * inv), f2bf(sv1 * inv), f2bf(sv2 * inv), f2bf(sv3 * inv));
  *(ushort4*)(Hr + 256 + 4 * l) = make_ushort4(
      f2bf(fmaxf(mv0, 0.f)), f2bf(fmaxf(mv1, 0.f)),
      f2bf(fmaxf(mv2, 0.f)), f2bf(fmaxf(mv3, 0.f)));
  if (l == 0)
    scal[local] = make_float4(sum_s * inv, dg > 0 ? mx_s : 0.f,
                              dg > 0 ? mn_s : 0.f, 0.f);
}

// ---- output GEMM with composite A, 128x128 tile ----------------------------
// 512 thr / 8 waves (4x2), wave 32x64, acc 2x4. A per K-step t:
//   t 0-1 : x (f32 -> bf16, reg-stage, swizzled ds_write)
//   t 2-5 : xp (global_load_lds, pre-swizzled source)
//   t 6-21: phase=(t-6)>>2, sub=(t-6)&3; own phases recompute from xp+scal,
//           oth phases gload_lds from Hg. own_first selects phase parity.
__global__ __launch_bounds__(512) void k_gemm_out(
    const float* __restrict__ x, const unsigned short* __restrict__ xp,
    const unsigned short* __restrict__ Hg, const float4* __restrict__ scal,
    const unsigned short* __restrict__ Wt, const float* __restrict__ bias,
    float* __restrict__ out, int Nloc, int own_first) {
  __shared__ unsigned short Ab[2][128 * 64];    // 16 KB x2
  __shared__ unsigned short Bb[2][128 * 64];    // 16 KB x2
  const int tid = threadIdx.x;
  const int l = tid & 63;
  const int lr = l & 15, lg = l >> 4;
  const int w = tid >> 6;                       // 0..7
  const int wr = w >> 1, wc = w & 1;            // 4 x 2 wave grid
  const int r0 = blockIdx.x * 128;
  const int wbase = tid & 448;                  // w*64, wave-uniform

  // two A-staging units per thread (128 rows x 8 chunks / 512 thr)
  int arw[2], acl[2], ar[2], asc[2];
  size_t adst[2];
  float ssv[2], mxv[2], mnv[2];
#pragma unroll
  for (int i = 0; i < 2; ++i) {
    int g = i * 512 + tid;
    arw[i] = g >> 3; acl[i] = g & 7;
    ar[i] = min(r0 + arw[i], Nloc - 1);
    asc[i] = acl[i] ^ (arw[i] & 7);
    adst[i] = (size_t)(arw[i] * 8 + asc[i]) * 8;
    float4 s4 = scal[ar[i]];
    ssv[i] = s4.x; mxv[i] = s4.y; mnv[i] = s4.z;
  }

  f32x4 acc[2][4];
#pragma unroll
  for (int m = 0; m < 2; ++m)
#pragma unroll
    for (int t = 0; t < 4; ++t) {
      f32x4 z = {0.f, 0.f, 0.f, 0.f};
      acc[m][t] = z;
    }

  auto stage = [&](int b, int t) {
#pragma unroll
    for (int i = 0; i < 2; ++i) {
      if (t < 2) {                               // x region: f32 reg-stage
        const float* src = x + (size_t)ar[i] * 128 + t * 64 + acl[i] * 8;
        float4 u = *(const float4*)src;
        float4 v = *(const float4*)(src + 4);
        bf16x8 h;
        h[0] = (short)f2bf(u.x); h[1] = (short)f2bf(u.y);
        h[2] = (short)f2bf(u.z); h[3] = (short)f2bf(u.w);
        h[4] = (short)f2bf(v.x); h[5] = (short)f2bf(v.y);
        h[6] = (short)f2bf(v.z); h[7] = (short)f2bf(v.w);
        *(bf16x8*)&Ab[b][adst[i]] = h;
      } else if (t < 6) {                        // xp region: direct gload_lds
        GLD16(xp + (size_t)ar[i] * 256 + (t - 2) * 64 + asc[i] * 8,
              &Ab[b][(size_t)(i * 512 + wbase) * 8]);
      } else {
        int phase = (t - 6) >> 2, sub = (t - 6) & 3;
        int is_own = own_first ? !(phase & 1) : (phase & 1);
        if (is_own) {                            // recompute from xp + scal
          bf16x8 v =
              *(const bf16x8*)(xp + (size_t)ar[i] * 256 + sub * 64 + acl[i] * 8);
          bf16x8 h;
          if (phase < 2) {                       // own-mean = ss * xp
#pragma unroll
            for (int q = 0; q < 8; ++q)
              h[q] = (short)f2bf(bf2f((unsigned short)v[q]) * ssv[i]);
          } else {                               // own-max = clamp form
#pragma unroll
            for (int q = 0; q < 8; ++q) {
              float f = bf2f((unsigned short)v[q]);
              h[q] = (short)f2bf(fmaxf(fmaxf(f * mxv[i], f * mnv[i]), 0.f));
            }
          }
          *(bf16x8*)&Ab[b][adst[i]] = h;
        } else {                                 // gathered half from Hg
          int hoff = (phase >= 2 ? 256 : 0) + sub * 64;
          GLD16(Hg + (size_t)ar[i] * 512 + hoff + asc[i] * 8,
                &Ab[b][(size_t)(i * 512 + wbase) * 8]);
        }
      }
    }
    int kb = t * 64;                             // B (128 rows x 64 cols)
#pragma unroll
    for (int i = 0; i < 2; ++i) {
      int g = i * 512 + tid;
      int row = g >> 3, c = g & 7;
      int sc = c ^ (row & 7);
      GLD16(Wt + (size_t)row * 1408 + kb + sc * 8,
            &Bb[b][(size_t)(i * 512 + wbase) * 8]);
    }
  };

  auto compute = [&](int b) {
#pragma unroll
    for (int kk = 0; kk < 2; ++kk) {
      int chq = kk * 4 + lg;
      bf16x8 a[2], bt[4];
#pragma unroll
      for (int m = 0; m < 2; ++m) {
        int row = wr * 32 + m * 16 + lr;
        a[m] = *(const bf16x8*)&Ab[b][(row * 8 + (chq ^ (row & 7))) * 8];
      }
#pragma unroll
      for (int t = 0; t < 4; ++t) {
        int row = wc * 64 + t * 16 + lr;
        bt[t] = *(const bf16x8*)&Bb[b][(row * 8 + (chq ^ (row & 7))) * 8];
      }
#pragma unroll
      for (int m = 0; m < 2; ++m)
#pragma unroll
        for (int t = 0; t < 4; ++t)
          acc[m][t] = __builtin_amdgcn_mfma_f32_16x16x32_bf16(
              a[m], bt[t], acc[m][t], 0, 0, 0);
    }
  };

  stage(0, 0);
  __syncthreads();
  int cur = 0;
  for (int t = 0; t < 22; ++t) {                // 22 * 64 = K = 1408
    if (t < 21) stage(cur ^ 1, t + 1);
    compute(cur);
    __syncthreads();
    cur ^= 1;
  }

#pragma unroll
  for (int m = 0; m < 2; ++m) {
    int rb = r0 + wr * 32 + m * 16 + lg * 4;    // C/D: col=lane&15, row=lg*4+reg
#pragma unroll
    for (int t = 0; t < 4; ++t) {
      int c = wc * 64 + t * 16 + lr;
      float bbias = bias[c];
#pragma unroll
      for (int r = 0; r < 4; ++r) {
        int rr = rb + r;
        if (rr < Nloc) out[(size_t)rr * 128 + c] = fmaxf(acc[m][t][r] + bbias, 0.f);
      }
    }
  }
}

extern "C" void kernel_launch(void* const* d_in, const int* in_sizes, int n_in,
                              void* d_out, int out_size, void* d_ws,
                              size_t ws_size, hipStream_t stream) {
  const float* x_i  = (const float*)d_in[0];
  const float* x_m  = (const float*)d_in[1];
  const int*   ei   = (const int*)d_in[2];
  const float* Wi_i = (const float*)d_in[3];
  const float* bi_i = (const float*)d_in[4];
  const float* Wi_m = (const float*)d_in[5];
  const float* bi_m = (const float*)d_in[6];
  const float* Wsc  = (const float*)d_in[7];
  const float* bsc  = (const float*)d_in[8];
  const float* Wo_i = (const float*)d_in[9];
  const float* bo_i = (const float*)d_in[10];
  const float* Wo_m = (const float*)d_in[11];
  const float* bo_m = (const float*)d_in[12];
  float* out = (float*)d_out;

  int Ni = in_sizes[0] / 128, Nm = in_sizes[1] / 128, E = in_sizes[2] / 2;
  const int* es = ei;
  const int* ee = ei + E;
  int nbi = (Ni + 255) / 256, nbm = (Nm + 255) / 256;   // <= 1024 assumed

  char* p = (char*)d_ws;
  auto alloc = [&](size_t bytes) {
    char* q = p;
    p += (bytes + 255) & ~(size_t)255;
    return q;
  };
  unsigned short* xp_i = (unsigned short*)alloc((size_t)Ni * 256 * 2);
  unsigned short* xp_m = (unsigned short*)alloc((size_t)Nm * 256 * 2);
  float* a_i   = (float*)alloc((size_t)Ni * 4);
  float* a_m   = (float*)alloc((size_t)Nm * 4);
  int* deg_i   = (int*)alloc((size_t)Ni * 4);
  int* deg_m   = (int*)alloc((size_t)Nm * 4);
  int* rp_i    = (int*)alloc((size_t)(Ni + 1) * 4);
  int* rp_m    = (int*)alloc((size_t)(Nm + 1) * 4);
  int* cur_i   = (int*)alloc((size_t)Ni * 4);
  int* cur_m   = (int*)alloc((size_t)Nm * 4);
  int* bs_i    = (int*)alloc((size_t)nbi * 4);
  int* bs_m    = (int*)alloc((size_t)nbm * 4);
  int* bb_i    = (int*)alloc((size_t)nbi * 4);
  int* bb_m    = (int*)alloc((size_t)nbm * 4);
  int* col_i   = (int*)alloc((size_t)E * 4);
  int* col_m   = (int*)alloc((size_t)E * 4);
  float* sv_i  = (float*)alloc((size_t)E * 4);
  float* sv_m  = (float*)alloc((size_t)E * 4);
  unsigned short* Wt_i = (unsigned short*)alloc((size_t)128 * 1408 * 2);
  unsigned short* Wt_m = (unsigned short*)alloc((size_t)128 * 1408 * 2);
  unsigned short* Wint_i = (unsigned short*)alloc((size_t)256 * 128 * 2);
  unsigned short* Wint_m = (unsigned short*)alloc((size_t)256 * 128 * 2);

  size_t used = (size_t)(p - (char*)d_ws);
  if (used + 256 > ws_size) return;
  size_t avail = ws_size - used - 256;
  // slab rows cost: 512 bf16 (Hg) + float4 (scal) = 1040 B
  long long srows_ll = (long long)(avail / 1040);
  int maxN = (Ni > Nm ? Ni : Nm);
  int maxPad = (maxN + 127) & ~127;
  int S = (int)(srows_ll > maxPad ? maxPad : srows_ll);
  S &= ~127;
  if (S < 128) return;
  unsigned short* Hg = (unsigned short*)alloc((size_t)S * 512 * 2);
  float4* scal = (float4*)alloc((size_t)S * 16);

  hipMemsetAsync(deg_i, 0, (size_t)Ni * 4, stream);
  hipMemsetAsync(deg_m, 0, (size_t)Nm * 4, stream);
  hipMemsetAsync(a_i, 0, (size_t)Ni * 4, stream);
  hipMemsetAsync(a_m, 0, (size_t)Nm * 4, stream);

  k_prep_wt<<<(1408 * 128 + 255) / 256, 256, 0, stream>>>(Wo_i, Wt_i, 1408, 128);
  k_prep_wt<<<(1408 * 128 + 255) / 256, 256, 0, stream>>>(Wo_m, Wt_m, 1408, 128);
  k_prep_wt<<<(128 * 256 + 255) / 256, 256, 0, stream>>>(Wi_i, Wint_i, 128, 256);
  k_prep_wt<<<(128 * 256 + 255) / 256, 256, 0, stream>>>(Wi_m, Wint_m, 128, 256);

  k_gemm_in<<<(Ni + 63) / 64, 256, 0, stream>>>(x_i, Wint_i, bi_i, Wsc, xp_i, a_i, Ni);
  k_gemm_in<<<(Nm + 63) / 64, 256, 0, stream>>>(x_m, Wint_m, bi_m, Wsc + 256, xp_m, a_m, Nm);

  k_deg<<<(E + 255) / 256, 256, 0, stream>>>(es, ee, E, deg_i, deg_m);
  k_scan_blk<<<nbi, 256, 0, stream>>>(deg_i, bs_i, Ni);
  k_scan_blk<<<nbm, 256, 0, stream>>>(deg_m, bs_m, Nm);
  k_scan_top<<<2, 1024, 0, stream>>>(bs_i, bb_i, nbi, bs_m, bb_m, nbm);
  k_scan_wr<<<nbi, 256, 0, stream>>>(deg_i, bb_i, rp_i, cur_i, Ni, E);
  k_scan_wr<<<nbm, 256, 0, stream>>>(deg_m, bb_m, rp_m, cur_m, Nm, E);
  k_fill<<<(E + 255) / 256, 256, 0, stream>>>(es, ee, E, a_i, a_m, bsc,
                                              cur_i, col_i, sv_i,
                                              cur_m, col_m, sv_m);

  // intt side: own halves first in pooled blocks (own_first=1)
  for (int base = 0; base < Ni; base += S) {
    int cnt = Ni - base; if (cnt > S) cnt = S;
    k_agg<<<(cnt + 3) / 4, 256, 0, stream>>>(xp_m, rp_i, col_i, sv_i,
                                             Hg, scal, base, cnt);
    k_gemm_out<<<(cnt + 127) / 128, 512, 0, stream>>>(
        x_i + (size_t)base * 128, xp_i + (size_t)base * 256, Hg, scal,
        Wt_i, bo_i, out + (size_t)base * 128, cnt, 1);
  }
  // mvtx side: gathered halves first (own_first=0)
  float* out_m = out + (size_t)Ni * 128;
  for (int base = 0; base < Nm; base += S) {
    int cnt = Nm - base; if (cnt > S) cnt = S;
    k_agg<<<(cnt + 3) / 4, 256, 0, stream>>>(xp_i, rp_m, col_m, sv_m,
                                             Hg, scal, base, cnt);
    k_gemm_out<<<(cnt + 127) / 128, 512, 0, stream>>>(
        x_m + (size_t)base * 128, xp_m + (size_t)base * 256, Hg, scal,
        Wt_m, bo_m, out_m + (size_t)base * 128, cnt, 0);
  }
}

// Round 17
// 272.428 us; speedup vs baseline: 1.2914x; 1.0105x over previous
//
#include <hip/hip_runtime.h>

// ---------------------------------------------------------------------------
// BipartiteLayer: xp = x@W_in+b ; s = exp(-|[xp_i[s],xp_m[e]]@W_score+b|) ;
// scatter mean/max of xp_pair*s ; h = relu([x,xp,mean,max]@W_out+b)
//
// R17: k_gemm_out counted-vmcnt pipeline (T4 + T14 async-stage split).
// Raw s_barrier + s_waitcnt vmcnt(g(t+1)) instead of __syncthreads drain:
// stage(t+1)'s loads stay in flight across the barrier (in-order vmcnt
// retirement guarantees buf-t ready). Reg-staged phases issue loads before
// compute(t), ds_write after barrier #2. Value paths identical to R16.
// ---------------------------------------------------------------------------

typedef __attribute__((ext_vector_type(8))) short bf16x8;   // 8 bf16 = 4 VGPR
typedef __attribute__((ext_vector_type(4))) float f32x4;

static __device__ __forceinline__ unsigned short f2bf(float f) {
  unsigned int u = __float_as_uint(f);
  u = (u + 0x7FFFu + ((u >> 16) & 1u)) >> 16;   // RNE
  return (unsigned short)u;
}
static __device__ __forceinline__ float bf2f(unsigned short s) {
  return __uint_as_float(((unsigned int)s) << 16);
}

#define GLD16(gp, lp)                                                        \
  __builtin_amdgcn_global_load_lds(                                          \
      (const __attribute__((address_space(1))) void*)(gp),                   \
      (__attribute__((address_space(3))) void*)(lp), 16, 0, 0)

// ---- transpose W (KxNcol f32) -> Wt[col][k] bf16 ---------------------------
__global__ void k_prep_wt(const float* __restrict__ Wo,
                          unsigned short* __restrict__ Wt, int K, int Ncol) {
  int idx = blockIdx.x * blockDim.x + threadIdx.x;
  if (idx >= K * Ncol) return;
  int k = idx / Ncol, c = idx % Ncol;
  Wt[(size_t)c * K + k] = f2bf(Wo[idx]);
}

// ---- input GEMM (MFMA): [N,128]f32 @ [128,256] -> xp bf16, a=xp.Ws --------
__global__ __launch_bounds__(256) void k_gemm_in(
    const float* __restrict__ x, const unsigned short* __restrict__ Wint,
    const float* __restrict__ bias, const float* __restrict__ Wsc,
    unsigned short* __restrict__ xp, float* __restrict__ a_out, int N) {
  __shared__ __align__(16) unsigned short Ab[64 * 16 * 8];    // 16 KB
  __shared__ __align__(16) unsigned short Bb[256 * 16 * 8];   // 64 KB
  const int tid = threadIdx.x;
  const int l = tid & 63;
  const int lr = l & 15, lg = l >> 4;
  const int w = tid >> 6, wr = w >> 1, wc = w & 1;
  const int r0 = blockIdx.x * 64;
  const int wbase = tid & 192;                  // w*64, wave-uniform

#pragma unroll
  for (int i = 0; i < 16; ++i) {                // B: 256 rows x 16 chunks
    int g = i * 256 + tid;
    int row = g >> 4, c = g & 15;
    int sc = c ^ (row & 7);
    GLD16(Wint + (size_t)row * 128 + sc * 8,
          &Bb[(size_t)(i * 256 + wbase) * 8]);
  }
#pragma unroll
  for (int i = 0; i < 4; ++i) {                 // A: reg-stage f32->bf16
    int g = i * 256 + tid;
    int row = g >> 4, c = g & 15;
    int ar = min(r0 + row, N - 1);
    const float* src = x + (size_t)ar * 128 + c * 8;
    float4 u = *(const float4*)src;
    float4 v = *(const float4*)(src + 4);
    bf16x8 h;
    h[0] = (short)f2bf(u.x); h[1] = (short)f2bf(u.y);
    h[2] = (short)f2bf(u.z); h[3] = (short)f2bf(u.w);
    h[4] = (short)f2bf(v.x); h[5] = (short)f2bf(v.y);
    h[6] = (short)f2bf(v.z); h[7] = (short)f2bf(v.w);
    *(bf16x8*)&Ab[(size_t)(row * 16 + (c ^ (row & 7))) * 8] = h;
  }
  __syncthreads();

  f32x4 acc[2][8];
#pragma unroll
  for (int m = 0; m < 2; ++m)
#pragma unroll
    for (int t = 0; t < 8; ++t) {
      f32x4 z = {0.f, 0.f, 0.f, 0.f};
      acc[m][t] = z;
    }
#pragma unroll
  for (int kk = 0; kk < 4; ++kk) {
    int chq = kk * 4 + lg;
    bf16x8 a[2], bt[8];
#pragma unroll
    for (int m = 0; m < 2; ++m) {
      int row = wr * 32 + m * 16 + lr;
      a[m] = *(const bf16x8*)&Ab[(row * 16 + (chq ^ (row & 7))) * 8];
    }
#pragma unroll
    for (int t = 0; t < 8; ++t) {
      int row = wc * 128 + t * 16 + lr;
      bt[t] = *(const bf16x8*)&Bb[(row * 16 + (chq ^ (row & 7))) * 8];
    }
#pragma unroll
    for (int m = 0; m < 2; ++m)
#pragma unroll
      for (int t = 0; t < 8; ++t)
        acc[m][t] = __builtin_amdgcn_mfma_f32_16x16x32_bf16(
            a[m], bt[t], acc[m][t], 0, 0, 0);
  }

  float wscv[8], bb[8];
#pragma unroll
  for (int t = 0; t < 8; ++t) {
    int c = wc * 128 + t * 16 + lr;
    wscv[t] = Wsc[c];
    bb[t] = bias[c];
  }
#pragma unroll
  for (int m = 0; m < 2; ++m) {
    int rb = r0 + wr * 32 + m * 16 + lg * 4;    // C/D: col=lane&15, row=lg*4+reg
    float p0 = 0.f, p1 = 0.f, p2 = 0.f, p3 = 0.f;
#pragma unroll
    for (int t = 0; t < 8; ++t) {
      int c = wc * 128 + t * 16 + lr;
      float v0 = acc[m][t][0] + bb[t];
      float v1 = acc[m][t][1] + bb[t];
      float v2 = acc[m][t][2] + bb[t];
      float v3 = acc[m][t][3] + bb[t];
      if (rb + 0 < N) xp[(size_t)(rb + 0) * 256 + c] = f2bf(v0);
      if (rb + 1 < N) xp[(size_t)(rb + 1) * 256 + c] = f2bf(v1);
      if (rb + 2 < N) xp[(size_t)(rb + 2) * 256 + c] = f2bf(v2);
      if (rb + 3 < N) xp[(size_t)(rb + 3) * 256 + c] = f2bf(v3);
      p0 = fmaf(v0, wscv[t], p0); p1 = fmaf(v1, wscv[t], p1);
      p2 = fmaf(v2, wscv[t], p2); p3 = fmaf(v3, wscv[t], p3);
    }
#pragma unroll
    for (int off = 1; off < 16; off <<= 1) {
      p0 += __shfl_xor(p0, off); p1 += __shfl_xor(p1, off);
      p2 += __shfl_xor(p2, off); p3 += __shfl_xor(p3, off);
    }
    if (lr == 0) {
      if (rb + 0 < N) atomicAdd(a_out + rb + 0, p0);
      if (rb + 1 < N) atomicAdd(a_out + rb + 1, p1);
      if (rb + 2 < N) atomicAdd(a_out + rb + 2, p2);
      if (rb + 3 < N) atomicAdd(a_out + rb + 3, p3);
    }
  }
}

// ---- CSR build: degree histogram ------------------------------------------
__global__ void k_deg(const int* __restrict__ es, const int* __restrict__ ee,
                      int E, int* __restrict__ deg_i, int* __restrict__ deg_m) {
  int e = blockIdx.x * blockDim.x + threadIdx.x;
  if (e >= E) return;
  atomicAdd(deg_i + es[e], 1);
  atomicAdd(deg_m + ee[e], 1);
}

// ---- CSR scan phase 1 ------------------------------------------------------
__global__ __launch_bounds__(256) void k_scan_blk(
    const int* __restrict__ deg, int* __restrict__ blksum, int n) {
  __shared__ int sm[256];
  int t = threadIdx.x;
  int i = blockIdx.x * 256 + t;
  sm[t] = (i < n) ? deg[i] : 0;
  __syncthreads();
#pragma unroll
  for (int off = 128; off; off >>= 1) {
    if (t < off) sm[t] += sm[t + off];
    __syncthreads();
  }
  if (t == 0) blksum[blockIdx.x] = sm[0];
}

// ---- CSR scan phase 2 ------------------------------------------------------
__global__ __launch_bounds__(1024) void k_scan_top(
    const int* __restrict__ bs_i, int* __restrict__ bb_i, int nbi,
    const int* __restrict__ bs_m, int* __restrict__ bb_m, int nbm) {
  const int* bs = blockIdx.x ? bs_m : bs_i;
  int* bb = blockIdx.x ? bb_m : bb_i;
  int nb = blockIdx.x ? nbm : nbi;
  __shared__ int sm[1024];
  int t = threadIdx.x;
  int d = (t < nb) ? bs[t] : 0;
  sm[t] = d;
  __syncthreads();
  for (int off = 1; off < 1024; off <<= 1) {    // Hillis-Steele inclusive
    int v = (t >= off) ? sm[t - off] : 0;
    __syncthreads();
    sm[t] += v;
    __syncthreads();
  }
  if (t < nb) bb[t] = sm[t] - d;                // exclusive
}

// ---- CSR scan phase 3 ------------------------------------------------------
__global__ __launch_bounds__(256) void k_scan_wr(
    const int* __restrict__ deg, const int* __restrict__ blkbase,
    int* __restrict__ rp, int* __restrict__ cur, int n, int E) {
  __shared__ int sm[256];
  int t = threadIdx.x;
  int i = blockIdx.x * 256 + t;
  int d = (i < n) ? deg[i] : 0;
  sm[t] = d;
  __syncthreads();
  for (int off = 1; off < 256; off <<= 1) {     // Hillis-Steele inclusive
    int v = (t >= off) ? sm[t - off] : 0;
    __syncthreads();
    sm[t] += v;
    __syncthreads();
  }
  if (i < n) {
    int v = blkbase[blockIdx.x] + sm[t] - d;    // exclusive + block base
    rp[i] = v; cur[i] = v;
  }
  if (i == 0) rp[n] = E;
}

// ---- CSR build: score + fill ----------------------------------------------
__global__ void k_fill(const int* __restrict__ es, const int* __restrict__ ee,
                       int E, const float* __restrict__ a_i,
                       const float* __restrict__ a_m,
                       const float* __restrict__ bsc,
                       int* __restrict__ cur_i, int* __restrict__ col_i,
                       float* __restrict__ sv_i,
                       int* __restrict__ cur_m, int* __restrict__ col_m,
                       float* __restrict__ sv_m) {
  int e = blockIdx.x * blockDim.x + threadIdx.x;
  if (e >= E) return;
  int s = es[e], m = ee[e];
  float sc = expf(-fabsf(a_i[s] + a_m[m] + bsc[0]));
  int pi = atomicAdd(cur_i + s, 1);
  col_i[pi] = m; sv_i[pi] = sc;
  int pm = atomicAdd(cur_m + m, 1);
  col_m[pm] = s; sv_m[pm] = sc;
}

// ---- wave-per-node CSR aggregation -> Hg (512 gathered cols) + scal --------
__global__ __launch_bounds__(256) void k_agg(
    const unsigned short* __restrict__ xp_oth,
    const int* __restrict__ rowptr, const int* __restrict__ col,
    const float* __restrict__ sv, unsigned short* __restrict__ Hg,
    float4* __restrict__ scal, int base, int cnt) {
  int local = blockIdx.x * 4 + (threadIdx.x >> 6);
  if (local >= cnt) return;                      // wave-uniform
  int node = base + local;
  int l = threadIdx.x & 63;

  float sum_s = 0.f, mx_s = -1e30f, mn_s = 1e30f;
  float sv0 = 0.f, sv1 = 0.f, sv2 = 0.f, sv3 = 0.f;
  float mv0 = -1e30f, mv1 = -1e30f, mv2 = -1e30f, mv3 = -1e30f;
  int jb = rowptr[node], je = rowptr[node + 1];
  int dg = je - jb;
  int j = jb;
  for (; j + 3 < je; j += 4) {                   // 4 independent gathers
    int o0 = col[j], o1 = col[j + 1], o2 = col[j + 2], o3 = col[j + 3];
    float s0 = sv[j], s1 = sv[j + 1], s2 = sv[j + 2], s3 = sv[j + 3];
    ushort4 g0 = *(const ushort4*)(xp_oth + (size_t)o0 * 256 + 4 * l);
    ushort4 g1 = *(const ushort4*)(xp_oth + (size_t)o1 * 256 + 4 * l);
    ushort4 g2 = *(const ushort4*)(xp_oth + (size_t)o2 * 256 + 4 * l);
    ushort4 g3 = *(const ushort4*)(xp_oth + (size_t)o3 * 256 + 4 * l);
    float f0, f1, f2, f3;
    f0 = bf2f(g0.x); f1 = bf2f(g0.y); f2 = bf2f(g0.z); f3 = bf2f(g0.w);
    sv0 = fmaf(s0, f0, sv0); sv1 = fmaf(s0, f1, sv1);
    sv2 = fmaf(s0, f2, sv2); sv3 = fmaf(s0, f3, sv3);
    mv0 = fmaxf(mv0, s0 * f0); mv1 = fmaxf(mv1, s0 * f1);
    mv2 = fmaxf(mv2, s0 * f2); mv3 = fmaxf(mv3, s0 * f3);
    f0 = bf2f(g1.x); f1 = bf2f(g1.y); f2 = bf2f(g1.z); f3 = bf2f(g1.w);
    sv0 = fmaf(s1, f0, sv0); sv1 = fmaf(s1, f1, sv1);
    sv2 = fmaf(s1, f2, sv2); sv3 = fmaf(s1, f3, sv3);
    mv0 = fmaxf(mv0, s1 * f0); mv1 = fmaxf(mv1, s1 * f1);
    mv2 = fmaxf(mv2, s1 * f2); mv3 = fmaxf(mv3, s1 * f3);
    f0 = bf2f(g2.x); f1 = bf2f(g2.y); f2 = bf2f(g2.z); f3 = bf2f(g2.w);
    sv0 = fmaf(s2, f0, sv0); sv1 = fmaf(s2, f1, sv1);
    sv2 = fmaf(s2, f2, sv2); sv3 = fmaf(s2, f3, sv3);
    mv0 = fmaxf(mv0, s2 * f0); mv1 = fmaxf(mv1, s2 * f1);
    mv2 = fmaxf(mv2, s2 * f2); mv3 = fmaxf(mv3, s2 * f3);
    f0 = bf2f(g3.x); f1 = bf2f(g3.y); f2 = bf2f(g3.z); f3 = bf2f(g3.w);
    sv0 = fmaf(s3, f0, sv0); sv1 = fmaf(s3, f1, sv1);
    sv2 = fmaf(s3, f2, sv2); sv3 = fmaf(s3, f3, sv3);
    mv0 = fmaxf(mv0, s3 * f0); mv1 = fmaxf(mv1, s3 * f1);
    mv2 = fmaxf(mv2, s3 * f2); mv3 = fmaxf(mv3, s3 * f3);
    sum_s += (s0 + s1) + (s2 + s3);
    mx_s = fmaxf(mx_s, fmaxf(fmaxf(s0, s1), fmaxf(s2, s3)));
    mn_s = fminf(mn_s, fminf(fminf(s0, s1), fminf(s2, s3)));
  }
  for (; j < je; ++j) {                          // tail 0..3
    int o0 = col[j];
    float s0 = sv[j];
    ushort4 g0 = *(const ushort4*)(xp_oth + (size_t)o0 * 256 + 4 * l);
    float f0 = bf2f(g0.x), f1 = bf2f(g0.y), f2 = bf2f(g0.z), f3 = bf2f(g0.w);
    sv0 = fmaf(s0, f0, sv0); sv1 = fmaf(s0, f1, sv1);
    sv2 = fmaf(s0, f2, sv2); sv3 = fmaf(s0, f3, sv3);
    mv0 = fmaxf(mv0, s0 * f0); mv1 = fmaxf(mv1, s0 * f1);
    mv2 = fmaxf(mv2, s0 * f2); mv3 = fmaxf(mv3, s0 * f3);
    sum_s += s0; mx_s = fmaxf(mx_s, s0); mn_s = fminf(mn_s, s0);
  }
  float inv = 1.f / (float)(dg > 0 ? dg : 1);
  unsigned short* Hr = Hg + (size_t)local * 512;
  *(ushort4*)(Hr + 4 * l) = make_ushort4(
      f2bf(sv0 * inv), f2bf(sv1 * inv), f2bf(sv2 * inv), f2bf(sv3 * inv));
  *(ushort4*)(Hr + 256 + 4 * l) = make_ushort4(
      f2bf(fmaxf(mv0, 0.f)), f2bf(fmaxf(mv1, 0.f)),
      f2bf(fmaxf(mv2, 0.f)), f2bf(fmaxf(mv3, 0.f)));
  if (l == 0)
    scal[local] = make_float4(sum_s * inv, dg > 0 ? mx_s : 0.f,
                              dg > 0 ? mn_s : 0.f, 0.f);
}

// ---- output GEMM, composite A, 128x128, counted-vmcnt pipeline -------------
// 512 thr / 8 waves (4x2), wave 32x64, acc 2x4, 2 LDS buffers.
// Per iter: wait vmcnt(g(t+1)) [in-order retirement => buf t ready],
// s_barrier, issue reg-loads for t+2, compute(t), s_barrier, GLD16(t+2) +
// reg->ds_write(t+2). g = per-thread GLD16 count: x/own = 2, xp/oth = 4.
template <int OWN_FIRST>
__global__ __launch_bounds__(512) void k_gemm_out(
    const float* __restrict__ x, const unsigned short* __restrict__ xp,
    const unsigned short* __restrict__ Hg, const float4* __restrict__ scal,
    const unsigned short* __restrict__ Wt, const float* __restrict__ bias,
    float* __restrict__ out, int Nloc) {
  __shared__ unsigned short Ab[2][128 * 64];    // 16 KB x2
  __shared__ unsigned short Bb[2][128 * 64];    // 16 KB x2
  const int tid = threadIdx.x;
  const int l = tid & 63;
  const int lr = l & 15, lg = l >> 4;
  const int w = tid >> 6;                       // 0..7
  const int wr = w >> 1, wc = w & 1;            // 4 x 2 wave grid
  const int r0 = blockIdx.x * 128;
  const int wbase = tid & 448;                  // w*64, wave-uniform

  int arw[2], acl[2], ar[2], asc[2];
  size_t adst[2];
  float ssv[2], mxv[2], mnv[2];
#pragma unroll
  for (int i = 0; i < 2; ++i) {
    int g = i * 512 + tid;
    arw[i] = g >> 3; acl[i] = g & 7;
    ar[i] = min(r0 + arw[i], Nloc - 1);
    asc[i] = acl[i] ^ (arw[i] & 7);
    adst[i] = (size_t)(arw[i] * 8 + asc[i]) * 8;
    float4 s4 = scal[ar[i]];
    ssv[i] = s4.x; mxv[i] = s4.y; mnv[i] = s4.z;
  }

  // phase type of K-step t: 0=x, 1=xp, 2=own(recompute), 3=oth(Hg)
  auto ptype = [](int t) -> int {
    if (t < 2) return 0;
    if (t < 6) return 1;
    int phase = (t - 6) >> 2;
    int own = OWN_FIRST ? !(phase & 1) : (phase & 1);
    return own ? 2 : 3;
  };
  // per-thread GLD16 count of step t (B contributes 2 always)
  auto gcnt = [&](int t) -> int {
    if (t > 21) return 0;
    int pt = ptype(t);
    return (pt == 1 || pt == 3) ? 4 : 2;
  };

  // pending reg data for reg-staged phases (static-indexed under unroll)
  float4 px4[2][2];
  bf16x8 pxp[2];

  auto stage_regload = [&](int t) {
    int pt = ptype(t);
    if (pt == 0) {
#pragma unroll
      for (int i = 0; i < 2; ++i) {
        const float* src = x + (size_t)ar[i] * 128 + t * 64 + acl[i] * 8;
        px4[i][0] = *(const float4*)src;
        px4[i][1] = *(const float4*)(src + 4);
      }
    } else if (pt == 2) {
      int sub = (t - 6) & 3;
#pragma unroll
      for (int i = 0; i < 2; ++i)
        pxp[i] = *(const bf16x8*)(xp + (size_t)ar[i] * 256 + sub * 64 +
                                  acl[i] * 8);
    }
  };

  auto stage_gld = [&](int t, int b) {
    int pt = ptype(t);
    if (pt == 1) {
#pragma unroll
      for (int i = 0; i < 2; ++i)
        GLD16(xp + (size_t)ar[i] * 256 + (t - 2) * 64 + asc[i] * 8,
              &Ab[b][(size_t)(i * 512 + wbase) * 8]);
    } else if (pt == 3) {
      int phase = (t - 6) >> 2, sub = (t - 6) & 3;
      int hoff = (phase >= 2 ? 256 : 0) + sub * 64;
#pragma unroll
      for (int i = 0; i < 2; ++i)
        GLD16(Hg + (size_t)ar[i] * 512 + hoff + asc[i] * 8,
              &Ab[b][(size_t)(i * 512 + wbase) * 8]);
    }
    int kb = t * 64;                             // B (128 rows x 64 cols)
#pragma unroll
    for (int i = 0; i < 2; ++i) {
      int g = i * 512 + tid;
      int row = g >> 3, c = g & 7;
      int sc = c ^ (row & 7);
      GLD16(Wt + (size_t)row * 1408 + kb + sc * 8,
            &Bb[b][(size_t)(i * 512 + wbase) * 8]);
    }
  };

  auto stage_write = [&](int t, int b) {
    int pt = ptype(t);
    if (pt == 0) {
#pragma unroll
      for (int i = 0; i < 2; ++i) {
        bf16x8 h;
        h[0] = (short)f2bf(px4[i][0].x); h[1] = (short)f2bf(px4[i][0].y);
        h[2] = (short)f2bf(px4[i][0].z); h[3] = (short)f2bf(px4[i][0].w);
        h[4] = (short)f2bf(px4[i][1].x); h[5] = (short)f2bf(px4[i][1].y);
        h[6] = (short)f2bf(px4[i][1].z); h[7] = (short)f2bf(px4[i][1].w);
        *(bf16x8*)&Ab[b][adst[i]] = h;
      }
    } else if (pt == 2) {
      int phase = (t - 6) >> 2;
#pragma unroll
      for (int i = 0; i < 2; ++i) {
        bf16x8 h;
        if (phase < 2) {                         // own-mean = ss * xp
#pragma unroll
          for (int q = 0; q < 8; ++q)
            h[q] = (short)f2bf(bf2f((unsigned short)pxp[i][q]) * ssv[i]);
        } else {                                 // own-max = clamp form
#pragma unroll
          for (int q = 0; q < 8; ++q) {
            float f = bf2f((unsigned short)pxp[i][q]);
            h[q] = (short)f2bf(fmaxf(fmaxf(f * mxv[i], f * mnv[i]), 0.f));
          }
        }
        *(bf16x8*)&Ab[b][adst[i]] = h;
      }
    }
  };

  f32x4 acc[2][4];
#pragma unroll
  for (int m = 0; m < 2; ++m)
#pragma unroll
    for (int t = 0; t < 4; ++t) {
      f32x4 z = {0.f, 0.f, 0.f, 0.f};
      acc[m][t] = z;
    }

  auto compute = [&](int b) {
#pragma unroll
    for (int kk = 0; kk < 2; ++kk) {
      int chq = kk * 4 + lg;
      bf16x8 a[2], bt[4];
#pragma unroll
      for (int m = 0; m < 2; ++m) {
        int row = wr * 32 + m * 16 + lr;
        a[m] = *(const bf16x8*)&Ab[b][(row * 8 + (chq ^ (row & 7))) * 8];
      }
#pragma unroll
      for (int t = 0; t < 4; ++t) {
        int row = wc * 64 + t * 16 + lr;
        bt[t] = *(const bf16x8*)&Bb[b][(row * 8 + (chq ^ (row & 7))) * 8];
      }
#pragma unroll
      for (int m = 0; m < 2; ++m)
#pragma unroll
        for (int t = 0; t < 4; ++t)
          acc[m][t] = __builtin_amdgcn_mfma_f32_16x16x32_bf16(
              a[m], bt[t], acc[m][t], 0, 0, 0);
    }
  };

  auto wait_cnt = [&](int n) {
    if (n >= 4)
      asm volatile("s_waitcnt vmcnt(4) lgkmcnt(0)" ::: "memory");
    else if (n >= 2)
      asm volatile("s_waitcnt vmcnt(2) lgkmcnt(0)" ::: "memory");
    else
      asm volatile("s_waitcnt vmcnt(0) lgkmcnt(0)" ::: "memory");
  };

  // prologue: fill both buffers (reg loads precede GLD16s so stage_write's
  // use-wait leaves the GLD16s in flight)
  stage_regload(0); stage_gld(0, 0); stage_write(0, 0);
  stage_regload(1); stage_gld(1, 1); stage_write(1, 1);

  for (int t = 0; t < 22; ++t) {
    int b = t & 1;
    wait_cnt(gcnt(t + 1));                      // buf t ready; t+1 stays in flight
    __builtin_amdgcn_s_barrier();
    __builtin_amdgcn_sched_barrier(0);
    if (t + 2 <= 21) stage_regload(t + 2);      // reg loads hide under compute
    compute(b);
    __builtin_amdgcn_s_barrier();               // all waves done reading buf b
    __builtin_amdgcn_sched_barrier(0);
    if (t + 2 <= 21) {
      stage_gld(t + 2, b);                      // refill buf b
      stage_write(t + 2, b);
    }
  }
  asm volatile("s_waitcnt vmcnt(0) lgkmcnt(0)" ::: "memory");

#pragma unroll
  for (int m = 0; m < 2; ++m) {
    int rb = r0 + wr * 32 + m * 16 + lg * 4;    // C/D: col=lane&15, row=lg*4+reg
#pragma unroll
    for (int t = 0; t < 4; ++t) {
      int c = wc * 64 + t * 16 + lr;
      float bbias = bias[c];
#pragma unroll
      for (int r = 0; r < 4; ++r) {
        int rr = rb + r;
        if (rr < Nloc) out[(size_t)rr * 128 + c] = fmaxf(acc[m][t][r] + bbias, 0.f);
      }
    }
  }
}

extern "C" void kernel_launch(void* const* d_in, const int* in_sizes, int n_in,
                              void* d_out, int out_size, void* d_ws,
                              size_t ws_size, hipStream_t stream) {
  const float* x_i  = (const float*)d_in[0];
  const float* x_m  = (const float*)d_in[1];
  const int*   ei   = (const int*)d_in[2];
  const float* Wi_i = (const float*)d_in[3];
  const float* bi_i = (const float*)d_in[4];
  const float* Wi_m = (const float*)d_in[5];
  const float* bi_m = (const float*)d_in[6];
  const float* Wsc  = (const float*)d_in[7];
  const float* bsc  = (const float*)d_in[8];
  const float* Wo_i = (const float*)d_in[9];
  const float* bo_i = (const float*)d_in[10];
  const float* Wo_m = (const float*)d_in[11];
  const float* bo_m = (const float*)d_in[12];
  float* out = (float*)d_out;

  int Ni = in_sizes[0] / 128, Nm = in_sizes[1] / 128, E = in_sizes[2] / 2;
  const int* es = ei;
  const int* ee = ei + E;
  int nbi = (Ni + 255) / 256, nbm = (Nm + 255) / 256;   // <= 1024 assumed

  char* p = (char*)d_ws;
  auto alloc = [&](size_t bytes) {
    char* q = p;
    p += (bytes + 255) & ~(size_t)255;
    return q;
  };
  unsigned short* xp_i = (unsigned short*)alloc((size_t)Ni * 256 * 2);
  unsigned short* xp_m = (unsigned short*)alloc((size_t)Nm * 256 * 2);
  float* a_i   = (float*)alloc((size_t)Ni * 4);
  float* a_m   = (float*)alloc((size_t)Nm * 4);
  int* deg_i   = (int*)alloc((size_t)Ni * 4);
  int* deg_m   = (int*)alloc((size_t)Nm * 4);
  int* rp_i    = (int*)alloc((size_t)(Ni + 1) * 4);
  int* rp_m    = (int*)alloc((size_t)(Nm + 1) * 4);
  int* cur_i   = (int*)alloc((size_t)Ni * 4);
  int* cur_m   = (int*)alloc((size_t)Nm * 4);
  int* bs_i    = (int*)alloc((size_t)nbi * 4);
  int* bs_m    = (int*)alloc((size_t)nbm * 4);
  int* bb_i    = (int*)alloc((size_t)nbi * 4);
  int* bb_m    = (int*)alloc((size_t)nbm * 4);
  int* col_i   = (int*)alloc((size_t)E * 4);
  int* col_m   = (int*)alloc((size_t)E * 4);
  float* sv_i  = (float*)alloc((size_t)E * 4);
  float* sv_m  = (float*)alloc((size_t)E * 4);
  unsigned short* Wt_i = (unsigned short*)alloc((size_t)128 * 1408 * 2);
  unsigned short* Wt_m = (unsigned short*)alloc((size_t)128 * 1408 * 2);
  unsigned short* Wint_i = (unsigned short*)alloc((size_t)256 * 128 * 2);
  unsigned short* Wint_m = (unsigned short*)alloc((size_t)256 * 128 * 2);

  size_t used = (size_t)(p - (char*)d_ws);
  if (used + 256 > ws_size) return;
  size_t avail = ws_size - used - 256;
  long long srows_ll = (long long)(avail / 1040);
  int maxN = (Ni > Nm ? Ni : Nm);
  int maxPad = (maxN + 127) & ~127;
  int S = (int)(srows_ll > maxPad ? maxPad : srows_ll);
  S &= ~127;
  if (S < 128) return;
  unsigned short* Hg = (unsigned short*)alloc((size_t)S * 512 * 2);
  float4* scal = (float4*)alloc((size_t)S * 16);

  hipMemsetAsync(deg_i, 0, (size_t)Ni * 4, stream);
  hipMemsetAsync(deg_m, 0, (size_t)Nm * 4, stream);
  hipMemsetAsync(a_i, 0, (size_t)Ni * 4, stream);
  hipMemsetAsync(a_m, 0, (size_t)Nm * 4, stream);

  k_prep_wt<<<(1408 * 128 + 255) / 256, 256, 0, stream>>>(Wo_i, Wt_i, 1408, 128);
  k_prep_wt<<<(1408 * 128 + 255) / 256, 256, 0, stream>>>(Wo_m, Wt_m, 1408, 128);
  k_prep_wt<<<(128 * 256 + 255) / 256, 256, 0, stream>>>(Wi_i, Wint_i, 128, 256);
  k_prep_wt<<<(128 * 256 + 255) / 256, 256, 0, stream>>>(Wi_m, Wint_m, 128, 256);

  k_gemm_in<<<(Ni + 63) / 64, 256, 0, stream>>>(x_i, Wint_i, bi_i, Wsc, xp_i, a_i, Ni);
  k_gemm_in<<<(Nm + 63) / 64, 256, 0, stream>>>(x_m, Wint_m, bi_m, Wsc + 256, xp_m, a_m, Nm);

  k_deg<<<(E + 255) / 256, 256, 0, stream>>>(es, ee, E, deg_i, deg_m);
  k_scan_blk<<<nbi, 256, 0, stream>>>(deg_i, bs_i, Ni);
  k_scan_blk<<<nbm, 256, 0, stream>>>(deg_m, bs_m, Nm);
  k_scan_top<<<2, 1024, 0, stream>>>(bs_i, bb_i, nbi, bs_m, bb_m, nbm);
  k_scan_wr<<<nbi, 256, 0, stream>>>(deg_i, bb_i, rp_i, cur_i, Ni, E);
  k_scan_wr<<<nbm, 256, 0, stream>>>(deg_m, bb_m, rp_m, cur_m, Nm, E);
  k_fill<<<(E + 255) / 256, 256, 0, stream>>>(es, ee, E, a_i, a_m, bsc,
                                              cur_i, col_i, sv_i,
                                              cur_m, col_m, sv_m);

  // intt side: own halves first in pooled blocks (OWN_FIRST=1)
  for (int base = 0; base < Ni; base += S) {
    int cnt = Ni - base; if (cnt > S) cnt = S;
    k_agg<<<(cnt + 3) / 4, 256, 0, stream>>>(xp_m, rp_i, col_i, sv_i,
                                             Hg, scal, base, cnt);
    k_gemm_out<1><<<(cnt + 127) / 128, 512, 0, stream>>>(
        x_i + (size_t)base * 128, xp_i + (size_t)base * 256, Hg, scal,
        Wt_i, bo_i, out + (size_t)base * 128, cnt);
  }
  // mvtx side: gathered halves first (OWN_FIRST=0)
  float* out_m = out + (size_t)Ni * 128;
  for (int base = 0; base < Nm; base += S) {
    int cnt = Nm - base; if (cnt > S) cnt = S;
    k_agg<<<(cnt + 3) / 4, 256, 0, stream>>>(xp_i, rp_m, col_m, sv_m,
                                             Hg, scal, base, cnt);
    k_gemm_out<0><<<(cnt + 127) / 128, 512, 0, stream>>>(
        x_m + (size_t)base * 128, xp_m + (size_t)base * 256, Hg, scal,
        Wt_m, bo_m, out_m + (size_t)base * 128, cnt);
  }
}